// Round 9
// baseline (361.456 us; speedup 1.0000x reference)
//
#include <hip/hip_runtime.h>

// GCN aggregation — bucketed partition + per-bucket counting sort +
// feature-sliced XCD-pinned register-accumulation aggregate.
//   out = diag(in_deg^-1/2) * A * diag(out_deg^-1/2) * concat(u_f, v_f)
//
// Pipeline:
//   init : gcurD[b]=gcurS[b]=b*BCAP
//   P1s  : partition src keys into 128-node buckets (LDS staged)
//   P2s  : per-bucket LDS histogram -> odeg
//   P1d  : partition edges by dst bucket, PACKED (d_local<<24|src) uint
//   sort : per-bucket counting sort -> sorted[] (src only, dst-ordered),
//          noffs[node], ndeg[node]   (runs ONCE per bucket, not per slice)
//   cast : sliced bf16 table  tbl[slice][node][16] = bf16(node_f * rsqrt(odeg))
//   agg  : block=(bucket,slice); slice=bid&7 -> pinned XCD (3.2MB slice table
//          L2-resident, proven R7/R8: FETCH ~60MB). Zero LDS: wave-per-node,
//          8 lanes/entry-group read sorted[] directly, 1 uint gather/lane,
//          shfl_xor reduce, fused in-norm.
//
// Fallback (small ws): round-5 slack-CSR random-atomic build + f32 gather.

#define DFEAT 128
#define SLACK 64
#define OVF2_CAP 65536
#define OVFD_CAP 65536
#define BSHIFT 7
#define BNODES 128
#define MAXBUK 1024         // supports nN <= 131072
#define BCAP 4096
#define CH 6144
#define NSLICE 8
#define SFEAT 16            // features per slice

// ---------------- init ----------------
__global__ void init_kernel(int* __restrict__ gcurD, int* __restrict__ gcurS,
                            int nbuk) {
    int b = blockIdx.x * blockDim.x + threadIdx.x;
    if (b < nbuk) { gcurD[b] = b * BCAP; gcurS[b] = b * BCAP; }
}

// ---------------- partition: (dst,src) pairs, packed flush ----------------
__global__ __launch_bounds__(256)
void partition_pairs_kernel(const int* __restrict__ dst,
                            const int* __restrict__ src,
                            int* __restrict__ gcur,
                            unsigned* __restrict__ part,   // packed uint
                            int2* __restrict__ ovf,
                            int* __restrict__ ovf_cnt,
                            int nE, int nbuk) {
    __shared__ int hist[MAXBUK];
    __shared__ int dlt[MAXBUK];
    __shared__ int wsum[4];
    __shared__ unsigned sk[CH];
    __shared__ unsigned sv[CH];

    int tid = threadIdx.x;
    long base = (long)blockIdx.x * CH;
    int n = (int)(((long)nE - base) < CH ? ((long)nE - base) : CH);
    if (n <= 0) return;

    for (int b = tid; b < nbuk; b += 256) hist[b] = 0;
    __syncthreads();
    for (int i = tid; i < n; i += 256)
        atomicAdd(&hist[((unsigned)dst[base + i]) >> BSHIFT], 1);
    __syncthreads();

    int b0 = tid * 4;
    int c0 = 0, c1 = 0, c2 = 0, c3 = 0, sum = 0;
    if (b0 < nbuk) {
        c0 = hist[b0];
        c1 = (b0 + 1 < nbuk) ? hist[b0 + 1] : 0;
        c2 = (b0 + 2 < nbuk) ? hist[b0 + 2] : 0;
        c3 = (b0 + 3 < nbuk) ? hist[b0 + 3] : 0;
        sum = c0 + c1 + c2 + c3;
    }
    int lane = tid & 63, wid = tid >> 6;
    int x = sum;
    #pragma unroll
    for (int off = 1; off < 64; off <<= 1) {
        int t = __shfl_up(x, off, 64);
        if (lane >= off) x += t;
    }
    if (lane == 63) wsum[wid] = x;
    __syncthreads();
    int wpre = 0;
    for (int w = 0; w < wid; ++w) wpre += wsum[w];
    int excl = wpre + x - sum;
    __syncthreads();
    if (b0 < nbuk) {
        int lb = excl;
        hist[b0] = lb;
        if (c0) { int g = atomicAdd(&gcur[b0], c0); dlt[b0] = g - lb; }
        lb += c0;
        if (b0 + 1 < nbuk) {
            hist[b0 + 1] = lb;
            if (c1) { int g = atomicAdd(&gcur[b0 + 1], c1); dlt[b0 + 1] = g - lb; }
            lb += c1;
        }
        if (b0 + 2 < nbuk) {
            hist[b0 + 2] = lb;
            if (c2) { int g = atomicAdd(&gcur[b0 + 2], c2); dlt[b0 + 2] = g - lb; }
            lb += c2;
        }
        if (b0 + 3 < nbuk) {
            hist[b0 + 3] = lb;
            if (c3) { int g = atomicAdd(&gcur[b0 + 3], c3); dlt[b0 + 3] = g - lb; }
        }
    }
    __syncthreads();

    for (int i = tid; i < n; i += 256) {
        unsigned d = (unsigned)dst[base + i];
        unsigned s = (unsigned)src[base + i];
        int slot = atomicAdd(&hist[d >> BSHIFT], 1);
        sk[slot] = d; sv[slot] = s;
    }
    __syncthreads();

    for (int i = tid; i < n; i += 256) {
        unsigned d = sk[i], s = sv[i];
        int b = (int)(d >> BSHIFT);
        long dest = (long)dlt[b] + i;
        long capend = (long)(b + 1) * BCAP;
        if (dest < capend) {
            part[dest] = ((d & (BNODES - 1)) << 24) | s;
        } else {
            int q = atomicAdd(ovf_cnt, 1);
            if (q < OVFD_CAP) ovf[q] = make_int2((int)d, (int)s);
        }
    }
}

// ---------------- partition: src keys only ----------------
__global__ __launch_bounds__(256)
void partition_keys_kernel(const int* __restrict__ key,
                           int* __restrict__ gcur,
                           unsigned* __restrict__ part,
                           int* __restrict__ spill_hist,  // odeg; spills add here
                           int nE, int nbuk) {
    __shared__ int hist[MAXBUK];
    __shared__ int dlt[MAXBUK];
    __shared__ int wsum[4];
    __shared__ unsigned sk[CH];

    int tid = threadIdx.x;
    long base = (long)blockIdx.x * CH;
    int n = (int)(((long)nE - base) < CH ? ((long)nE - base) : CH);
    if (n <= 0) return;

    for (int b = tid; b < nbuk; b += 256) hist[b] = 0;
    __syncthreads();
    for (int i = tid; i < n; i += 256)
        atomicAdd(&hist[((unsigned)key[base + i]) >> BSHIFT], 1);
    __syncthreads();

    int b0 = tid * 4;
    int c0 = 0, c1 = 0, c2 = 0, c3 = 0, sum = 0;
    if (b0 < nbuk) {
        c0 = hist[b0];
        c1 = (b0 + 1 < nbuk) ? hist[b0 + 1] : 0;
        c2 = (b0 + 2 < nbuk) ? hist[b0 + 2] : 0;
        c3 = (b0 + 3 < nbuk) ? hist[b0 + 3] : 0;
        sum = c0 + c1 + c2 + c3;
    }
    int lane = tid & 63, wid = tid >> 6;
    int x = sum;
    #pragma unroll
    for (int off = 1; off < 64; off <<= 1) {
        int t = __shfl_up(x, off, 64);
        if (lane >= off) x += t;
    }
    if (lane == 63) wsum[wid] = x;
    __syncthreads();
    int wpre = 0;
    for (int w = 0; w < wid; ++w) wpre += wsum[w];
    int excl = wpre + x - sum;
    __syncthreads();
    if (b0 < nbuk) {
        int lb = excl;
        hist[b0] = lb;
        if (c0) { int g = atomicAdd(&gcur[b0], c0); dlt[b0] = g - lb; }
        lb += c0;
        if (b0 + 1 < nbuk) {
            hist[b0 + 1] = lb;
            if (c1) { int g = atomicAdd(&gcur[b0 + 1], c1); dlt[b0 + 1] = g - lb; }
            lb += c1;
        }
        if (b0 + 2 < nbuk) {
            hist[b0 + 2] = lb;
            if (c2) { int g = atomicAdd(&gcur[b0 + 2], c2); dlt[b0 + 2] = g - lb; }
            lb += c2;
        }
        if (b0 + 3 < nbuk) {
            hist[b0 + 3] = lb;
            if (c3) { int g = atomicAdd(&gcur[b0 + 3], c3); dlt[b0 + 3] = g - lb; }
        }
    }
    __syncthreads();

    for (int i = tid; i < n; i += 256) {
        unsigned k = (unsigned)key[base + i];
        int slot = atomicAdd(&hist[k >> BSHIFT], 1);
        sk[slot] = k;
    }
    __syncthreads();

    for (int i = tid; i < n; i += 256) {
        unsigned k = sk[i];
        int b = (int)(k >> BSHIFT);
        long dest = (long)dlt[b] + i;
        long capend = (long)(b + 1) * BCAP;
        if (dest < capend) part[dest] = k;
        else atomicAdd(&spill_hist[k], 1);
    }
}

// ---------------- phase-2: odeg histogram ----------------
__global__ __launch_bounds__(256)
void odeg_phase2_kernel(const unsigned* __restrict__ part,
                        const int* __restrict__ gcur,
                        int* __restrict__ odeg, int nN) {
    __shared__ int bins[BNODES];
    int tid = threadIdx.x;
    int bucket = blockIdx.x;
    int nodeBase = bucket << BSHIFT;
    for (int b = tid; b < BNODES; b += 256) bins[b] = 0;
    __syncthreads();
    int start = bucket * BCAP;
    int endv = gcur[bucket];
    if (endv > start + BCAP) endv = start + BCAP;
    for (int i = start + tid; i < endv; i += 256)
        atomicAdd(&bins[(int)part[i] - nodeBase], 1);
    __syncthreads();
    for (int b = tid; b < BNODES; b += 256) {
        int node = nodeBase + b;
        if (node < nN && bins[b]) atomicAdd(&odeg[node], bins[b]);
    }
}

// ---------------- per-bucket counting sort ----------------
// partD (packed dl<<24|src) -> sorted (src only, grouped by dl) + noffs/ndeg.
__global__ __launch_bounds__(256)
void csr_sort_kernel(const unsigned* __restrict__ part,
                     const int* __restrict__ gcur,
                     unsigned* __restrict__ sorted,
                     int* __restrict__ noffs,
                     int* __restrict__ ndeg,
                     int nN) {
    __shared__ int bins[BNODES];
    __shared__ int w0tot;
    int tid = threadIdx.x;
    int bucket = blockIdx.x;
    int nodeBase = bucket << BSHIFT;
    if (tid < BNODES) bins[tid] = 0;
    __syncthreads();

    int start = bucket * BCAP;
    int endv  = gcur[bucket];
    if (endv > start + BCAP) endv = start + BCAP;

    for (int i = start + tid; i < endv; i += 256)
        atomicAdd(&bins[(int)(part[i] >> 24)], 1);
    __syncthreads();

    int lane = tid & 63, wid = tid >> 6;
    int v = 0, x = 0;
    if (tid < BNODES) {              // waves 0 and 1, fully active
        v = bins[tid];
        x = v;
        #pragma unroll
        for (int off = 1; off < 64; off <<= 1) {
            int t = __shfl_up(x, off, 64);
            if (lane >= off) x += t;
        }
        if (wid == 0 && lane == 63) w0tot = x;
    }
    __syncthreads();
    if (tid < BNODES) {
        int excl = x - v + (wid ? w0tot : 0);
        bins[tid] = excl;            // running cursor
        int node = nodeBase + tid;
        if (node < nN) { noffs[node] = start + excl; ndeg[node] = v; }
    }
    __syncthreads();

    for (int i = start + tid; i < endv; i += 256) {
        unsigned p = part[i];
        int dl = (int)(p >> 24);
        int pos = atomicAdd(&bins[dl], 1);
        sorted[start + pos] = p & 0xFFFFFFu;
    }
}

// ---------------- bf16 helpers ----------------
__device__ __forceinline__ unsigned short f2bf(float x) {
    unsigned u = __float_as_uint(x);
    u += 0x7fffu + ((u >> 16) & 1u);   // round-to-nearest-even
    return (unsigned short)(u >> 16);
}
__device__ __forceinline__ float bflo(unsigned u) { return __uint_as_float(u << 16); }
__device__ __forceinline__ float bfhi(unsigned u) { return __uint_as_float(u & 0xffff0000u); }

// ---------------- cast: sliced prescaled table ----------------
// tbl layout: [slice][node][16] bf16. One thread per float4 of the source row.
__global__ void cast_sliced_kernel(const float* __restrict__ u_f,
                                   const float* __restrict__ v_f,
                                   const int* __restrict__ odeg,
                                   unsigned short* __restrict__ tbl,
                                   int nN, int nU) {
    long i = (long)blockIdx.x * blockDim.x + threadIdx.x;
    long n4 = (long)nN * 32;
    if (i >= n4) return;
    int node = (int)(i >> 5);
    int q = (int)(i & 31);
    int slice = q >> 2, qi = q & 3;
    float norm = rsqrtf((float)max(odeg[node], 1));
    const float* base = (node < nU) ? (u_f + (size_t)node * DFEAT)
                                    : (v_f + (size_t)(node - nU) * DFEAT);
    float4 v = ((const float4*)base)[q];
    ushort4 o;
    o.x = f2bf(v.x * norm);
    o.y = f2bf(v.y * norm);
    o.z = f2bf(v.z * norm);
    o.w = f2bf(v.w * norm);
    ((ushort4*)tbl)[((size_t)slice * nN + node) * 4 + qi] = o;
}

// ---------------- aggregate: (bucket, slice) blocks, zero LDS ----------------
// slice = bid&7 -> pinned XCD; slice table (nN*32B ~ 3.2MB) L2-resident.
// Wave per node: 8 entry-groups x 8 feature-uints; sorted[] read directly.
__global__ __launch_bounds__(256)
void agg_sorted_kernel(const unsigned short* __restrict__ tbl,
                       const unsigned* __restrict__ sorted,
                       const int* __restrict__ noffs,
                       const int* __restrict__ ndeg,
                       const int2* __restrict__ ovfD,
                       const int* __restrict__ ovfD_cnt,
                       float* __restrict__ out,
                       int nN) {
    int tid = threadIdx.x;
    int slice  = blockIdx.x & (NSLICE - 1);
    int bucket = blockIdx.x >> 3;
    int nodeBase = bucket << BSHIFT;
    int lane = tid & 63;
    int wid  = tid >> 6;
    int eg   = lane >> 3;    // entry group 0..7
    int sub  = lane & 7;     // uint index within 16-feat row

    const unsigned* t4u = (const unsigned*)(tbl + (size_t)slice * nN * SFEAT);
    int m = *ovfD_cnt;                       // 0 in practice
    if (m > OVFD_CAP) m = OVFD_CAP;

    for (int nl = wid; nl < BNODES; nl += 4) {
        int node = nodeBase + nl;
        if (node >= nN) break;
        int begin = noffs[node];
        int deg   = ndeg[node];

        float a0 = 0.f, a1 = 0.f;
        int extra = 0;

        for (int k = eg; k < deg; k += 8) {
            unsigned s = sorted[begin + k];
            unsigned w = t4u[(size_t)s * 8 + sub];
            a0 += bflo(w); a1 += bfhi(w);
        }
        if (m > 0) {
            for (int j = eg; j < m; j += 8) {
                int2 e = ovfD[j];
                if (e.x == node) {
                    unsigned w = t4u[(size_t)e.y * 8 + sub];
                    a0 += bflo(w); a1 += bfhi(w);
                    ++extra;
                }
            }
        }

        a0 += __shfl_xor(a0, 8, 64);  a1 += __shfl_xor(a1, 8, 64);
        a0 += __shfl_xor(a0, 16, 64); a1 += __shfl_xor(a1, 16, 64);
        a0 += __shfl_xor(a0, 32, 64); a1 += __shfl_xor(a1, 32, 64);
        if (m > 0) {
            extra += __shfl_xor(extra, 8, 64);
            extra += __shfl_xor(extra, 16, 64);
            extra += __shfl_xor(extra, 32, 64);
        }

        if (lane < 8) {
            float inorm = rsqrtf((float)max(deg + extra, 1));
            ((float2*)(out + (size_t)node * DFEAT + slice * SFEAT))[lane] =
                make_float2(a0 * inorm, a1 * inorm);
        }
    }
}

// ---------------- fallback: round-5 random-atomic build ----------------
__global__ void build_kernel(const int* __restrict__ src,
                             const int* __restrict__ dst,
                             int* __restrict__ ideg,
                             int* __restrict__ odeg,
                             int* __restrict__ slack,
                             int2* __restrict__ ovf2,
                             int* __restrict__ ovf2_cnt,
                             int nE) {
    int t = blockIdx.x * blockDim.x + threadIdx.x;
    long base = (long)t * 4;
    if (base >= nE) return;
    long lim = base + 4 < (long)nE ? base + 4 : (long)nE;
    for (long e = base; e < lim; ++e) {
        int s = src[e], d = dst[e];
        atomicAdd(&odeg[s], 1);
        int p = atomicAdd(&ideg[d], 1);
        if (p < SLACK) {
            slack[(size_t)d * SLACK + p] = s;
        } else {
            int q = atomicAdd(ovf2_cnt, 1);
            if (q < OVF2_CAP) ovf2[q] = make_int2(d, s);
        }
    }
}

__launch_bounds__(256)
__global__ void aggregate_f32_kernel(const float* __restrict__ u_f,
                                     const float* __restrict__ v_f,
                                     const int* __restrict__ slack,
                                     const int* __restrict__ ideg,
                                     const int* __restrict__ odeg,
                                     const int2* __restrict__ ovf2,
                                     const int* __restrict__ ovf2_cnt,
                                     float* __restrict__ out,
                                     int nN, int nU) {
    int lane = threadIdx.x & 63;
    int wid  = threadIdx.x >> 6;
    int node = blockIdx.x * 4 + wid;
    if (node >= nN) return;

    int deg = ideg[node];
    int cnt = min(deg, SLACK);
    int   sb = 0;
    float nb = 0.f;
    if (lane < cnt) {
        sb = slack[(size_t)node * SLACK + lane];
        nb = rsqrtf((float)max(odeg[sb], 1));
    }
    float2 acc = make_float2(0.f, 0.f);
    for (int k = 0; k < cnt; ++k) {
        int   sk = __shfl(sb, k, 64);
        float nk = __shfl(nb, k, 64);
        const float* row = (sk < nU) ? (u_f + (size_t)sk * DFEAT)
                                     : (v_f + (size_t)(sk - nU) * DFEAT);
        float2 v = ((const float2*)row)[lane];
        acc.x += v.x * nk;
        acc.y += v.y * nk;
    }
    if (deg > SLACK) {
        int m = *ovf2_cnt; if (m > OVF2_CAP) m = OVF2_CAP;
        for (int j = 0; j < m; ++j) {
            int2 os = ovf2[j];
            if (os.x == node) {
                int sk = os.y;
                float nk = rsqrtf((float)max(odeg[sk], 1));
                const float* row = (sk < nU) ? (u_f + (size_t)sk * DFEAT)
                                             : (v_f + (size_t)(sk - nU) * DFEAT);
                float2 v = ((const float2*)row)[lane];
                acc.x += v.x * nk;
                acc.y += v.y * nk;
            }
        }
    }
    float inorm = rsqrtf((float)max(deg, 1));
    acc.x *= inorm; acc.y *= inorm;
    ((float2*)(out + (size_t)node * DFEAT))[lane] = acc;
}

extern "C" void kernel_launch(void* const* d_in, const int* in_sizes, int n_in,
                              void* d_out, int out_size, void* d_ws, size_t ws_size,
                              hipStream_t stream) {
    const float* u_f = (const float*)d_in[0];
    const float* v_f = (const float*)d_in[1];
    const int*   src = (const int*)d_in[2];
    const int*   dst = (const int*)d_in[3];
    float* out = (float*)d_out;

    int nU = in_sizes[0] / DFEAT;
    int nV = in_sizes[1] / DFEAT;
    int nN = nU + nV;
    int nE = in_sizes[2];
    int nbuk = (nN + BNODES - 1) >> BSHIFT;

    // ---- new-path workspace layout (ints) ----
    // fixed | sorted | partS | partD ; tbl overlays (partS,partD) after sort.
    int*  odeg  = (int*)d_ws;
    int*  cnts  = odeg + nN;                 // [1] = ovfD_cnt
    int2* ovfD  = (int2*)(cnts + 8);
    int*  gcurD = (int*)(ovfD + OVFD_CAP);
    int*  gcurS = gcurD + MAXBUK;
    int*  noffs = gcurS + MAXBUK;
    int*  ndeg  = noffs + nN;
    unsigned* sorted = (unsigned*)(ndeg + nN);
    size_t partInts = (size_t)nbuk * BCAP;
    unsigned* partS = sorted + partInts;
    unsigned* partD = partS + partInts;
    unsigned short* tbl = (unsigned short*)partS;   // overlays partS+partD
    size_t fixedInts = (size_t)3 * nN + 8 + 2 * (size_t)OVFD_CAP + 2 * MAXBUK;
    size_t tblInts   = (size_t)nN * (DFEAT / 2);
    size_t tailInts  = (2 * partInts > tblInts) ? 2 * partInts : tblInts;
    size_t needNew   = (fixedInts + partInts + tailInts) * 4;
    bool use_new = (nN <= (MAXBUK << BSHIFT)) && (nN < (1 << 24))
                   && (ws_size >= needNew);

    if (use_new) {
        hipMemsetAsync(d_ws, 0, ((size_t)nN + 8) * sizeof(int), stream);
        int nCh = (nE + CH - 1) / CH;
        init_kernel<<<(nbuk + 255) / 256, 256, 0, stream>>>(gcurD, gcurS, nbuk);
        partition_keys_kernel<<<nCh, 256, 0, stream>>>(src, gcurS, partS, odeg,
                                                       nE, nbuk);
        odeg_phase2_kernel<<<nbuk, 256, 0, stream>>>(partS, gcurS, odeg, nN);
        partition_pairs_kernel<<<nCh, 256, 0, stream>>>(dst, src, gcurD, partD,
                                                        ovfD, cnts + 1, nE, nbuk);
        csr_sort_kernel<<<nbuk, 256, 0, stream>>>(partD, gcurD, sorted,
                                                  noffs, ndeg, nN);
        {   // cast AFTER csr_sort: tbl overwrites partS+partD (both dead)
            long n4 = (long)nN * 32;
            cast_sliced_kernel<<<(int)((n4 + 255) / 256), 256, 0, stream>>>(
                u_f, v_f, odeg, tbl, nN, nU);
        }
        agg_sorted_kernel<<<nbuk * NSLICE, 256, 0, stream>>>(tbl, sorted, noffs,
                                                             ndeg, ovfD, cnts + 1,
                                                             out, nN);
    } else {
        // ---- fallback: round-5 layout ----
        int*  f_ideg = (int*)d_ws;
        int*  f_odeg = f_ideg + nN;
        int*  f_cnts = f_odeg + nN;          // [0] = ovf2_cnt
        int2* f_ovf2 = (int2*)(f_cnts + 8);
        int*  f_slack = (int*)(f_ovf2 + OVF2_CAP);

        hipMemsetAsync(d_ws, 0, ((size_t)2 * nN + 8) * sizeof(int), stream);
        long nT = ((long)nE + 3) / 4;
        build_kernel<<<(int)((nT + 255) / 256), 256, 0, stream>>>(
            src, dst, f_ideg, f_odeg, f_slack, f_ovf2, f_cnts + 0, nE);
        aggregate_f32_kernel<<<(nN + 3) / 4, 256, 0, stream>>>(
            u_f, v_f, f_slack, f_ideg, f_odeg, f_ovf2, f_cnts + 0, out, nN, nU);
    }
}

// Round 10
// 312.741 us; speedup vs baseline: 1.1558x; 1.1558x over previous
//
#include <hip/hip_runtime.h>

// GCN aggregation — bucketed partition + per-bucket counting sort +
// feature-sliced XCD-pinned aggregate with register entry-list (no dependent
// load chain: entries preloaded per node, gather addresses via __shfl).
//   out = diag(in_deg^-1/2) * A * diag(out_deg^-1/2) * concat(u_f, v_f)
//
// Pipeline:
//   init : gcurD[b]=gcurS[b]=b*BCAP
//   P1s  : partition src keys into 128-node buckets (LDS staged)
//   P2s  : per-bucket LDS histogram -> odeg
//   P1d  : partition edges by dst bucket, PACKED (d_local<<24|src) uint
//   sort : per-bucket counting sort -> sorted[] + noffs/ndeg (once per bucket)
//   cast : sliced bf16 table  tbl[slice][node][16] = bf16(node_f * rsqrt(odeg))
//   agg  : block=(bucket,slice); slice=bid&7 -> pinned XCD (3.2MB slice table
//          L2-resident; FETCH ~60-75MB proven R7-R9). Wave per node:
//          preload sorted[begin+lane] once, then 16 entries/instr
//          (4 lanes x uint2 = 32B row), x2 unroll, shfl_xor reduce.
//
// Fallback (small ws): round-5 slack-CSR random-atomic build + f32 gather.

#define DFEAT 128
#define SLACK 64
#define OVF2_CAP 65536
#define OVFD_CAP 65536
#define BSHIFT 7
#define BNODES 128
#define MAXBUK 1024         // supports nN <= 131072
#define BCAP 4096
#define CH 6144
#define NSLICE 8
#define SFEAT 16            // features per slice

// ---------------- init ----------------
__global__ void init_kernel(int* __restrict__ gcurD, int* __restrict__ gcurS,
                            int nbuk) {
    int b = blockIdx.x * blockDim.x + threadIdx.x;
    if (b < nbuk) { gcurD[b] = b * BCAP; gcurS[b] = b * BCAP; }
}

// ---------------- partition: (dst,src) pairs, packed flush ----------------
__global__ __launch_bounds__(256)
void partition_pairs_kernel(const int* __restrict__ dst,
                            const int* __restrict__ src,
                            int* __restrict__ gcur,
                            unsigned* __restrict__ part,   // packed uint
                            int2* __restrict__ ovf,
                            int* __restrict__ ovf_cnt,
                            int nE, int nbuk) {
    __shared__ int hist[MAXBUK];
    __shared__ int dlt[MAXBUK];
    __shared__ int wsum[4];
    __shared__ unsigned sk[CH];
    __shared__ unsigned sv[CH];

    int tid = threadIdx.x;
    long base = (long)blockIdx.x * CH;
    int n = (int)(((long)nE - base) < CH ? ((long)nE - base) : CH);
    if (n <= 0) return;

    for (int b = tid; b < nbuk; b += 256) hist[b] = 0;
    __syncthreads();
    for (int i = tid; i < n; i += 256)
        atomicAdd(&hist[((unsigned)dst[base + i]) >> BSHIFT], 1);
    __syncthreads();

    int b0 = tid * 4;
    int c0 = 0, c1 = 0, c2 = 0, c3 = 0, sum = 0;
    if (b0 < nbuk) {
        c0 = hist[b0];
        c1 = (b0 + 1 < nbuk) ? hist[b0 + 1] : 0;
        c2 = (b0 + 2 < nbuk) ? hist[b0 + 2] : 0;
        c3 = (b0 + 3 < nbuk) ? hist[b0 + 3] : 0;
        sum = c0 + c1 + c2 + c3;
    }
    int lane = tid & 63, wid = tid >> 6;
    int x = sum;
    #pragma unroll
    for (int off = 1; off < 64; off <<= 1) {
        int t = __shfl_up(x, off, 64);
        if (lane >= off) x += t;
    }
    if (lane == 63) wsum[wid] = x;
    __syncthreads();
    int wpre = 0;
    for (int w = 0; w < wid; ++w) wpre += wsum[w];
    int excl = wpre + x - sum;
    __syncthreads();
    if (b0 < nbuk) {
        int lb = excl;
        hist[b0] = lb;
        if (c0) { int g = atomicAdd(&gcur[b0], c0); dlt[b0] = g - lb; }
        lb += c0;
        if (b0 + 1 < nbuk) {
            hist[b0 + 1] = lb;
            if (c1) { int g = atomicAdd(&gcur[b0 + 1], c1); dlt[b0 + 1] = g - lb; }
            lb += c1;
        }
        if (b0 + 2 < nbuk) {
            hist[b0 + 2] = lb;
            if (c2) { int g = atomicAdd(&gcur[b0 + 2], c2); dlt[b0 + 2] = g - lb; }
            lb += c2;
        }
        if (b0 + 3 < nbuk) {
            hist[b0 + 3] = lb;
            if (c3) { int g = atomicAdd(&gcur[b0 + 3], c3); dlt[b0 + 3] = g - lb; }
        }
    }
    __syncthreads();

    for (int i = tid; i < n; i += 256) {
        unsigned d = (unsigned)dst[base + i];
        unsigned s = (unsigned)src[base + i];
        int slot = atomicAdd(&hist[d >> BSHIFT], 1);
        sk[slot] = d; sv[slot] = s;
    }
    __syncthreads();

    for (int i = tid; i < n; i += 256) {
        unsigned d = sk[i], s = sv[i];
        int b = (int)(d >> BSHIFT);
        long dest = (long)dlt[b] + i;
        long capend = (long)(b + 1) * BCAP;
        if (dest < capend) {
            part[dest] = ((d & (BNODES - 1)) << 24) | s;
        } else {
            int q = atomicAdd(ovf_cnt, 1);
            if (q < OVFD_CAP) ovf[q] = make_int2((int)d, (int)s);
        }
    }
}

// ---------------- partition: src keys only ----------------
__global__ __launch_bounds__(256)
void partition_keys_kernel(const int* __restrict__ key,
                           int* __restrict__ gcur,
                           unsigned* __restrict__ part,
                           int* __restrict__ spill_hist,  // odeg; spills add here
                           int nE, int nbuk) {
    __shared__ int hist[MAXBUK];
    __shared__ int dlt[MAXBUK];
    __shared__ int wsum[4];
    __shared__ unsigned sk[CH];

    int tid = threadIdx.x;
    long base = (long)blockIdx.x * CH;
    int n = (int)(((long)nE - base) < CH ? ((long)nE - base) : CH);
    if (n <= 0) return;

    for (int b = tid; b < nbuk; b += 256) hist[b] = 0;
    __syncthreads();
    for (int i = tid; i < n; i += 256)
        atomicAdd(&hist[((unsigned)key[base + i]) >> BSHIFT], 1);
    __syncthreads();

    int b0 = tid * 4;
    int c0 = 0, c1 = 0, c2 = 0, c3 = 0, sum = 0;
    if (b0 < nbuk) {
        c0 = hist[b0];
        c1 = (b0 + 1 < nbuk) ? hist[b0 + 1] : 0;
        c2 = (b0 + 2 < nbuk) ? hist[b0 + 2] : 0;
        c3 = (b0 + 3 < nbuk) ? hist[b0 + 3] : 0;
        sum = c0 + c1 + c2 + c3;
    }
    int lane = tid & 63, wid = tid >> 6;
    int x = sum;
    #pragma unroll
    for (int off = 1; off < 64; off <<= 1) {
        int t = __shfl_up(x, off, 64);
        if (lane >= off) x += t;
    }
    if (lane == 63) wsum[wid] = x;
    __syncthreads();
    int wpre = 0;
    for (int w = 0; w < wid; ++w) wpre += wsum[w];
    int excl = wpre + x - sum;
    __syncthreads();
    if (b0 < nbuk) {
        int lb = excl;
        hist[b0] = lb;
        if (c0) { int g = atomicAdd(&gcur[b0], c0); dlt[b0] = g - lb; }
        lb += c0;
        if (b0 + 1 < nbuk) {
            hist[b0 + 1] = lb;
            if (c1) { int g = atomicAdd(&gcur[b0 + 1], c1); dlt[b0 + 1] = g - lb; }
            lb += c1;
        }
        if (b0 + 2 < nbuk) {
            hist[b0 + 2] = lb;
            if (c2) { int g = atomicAdd(&gcur[b0 + 2], c2); dlt[b0 + 2] = g - lb; }
            lb += c2;
        }
        if (b0 + 3 < nbuk) {
            hist[b0 + 3] = lb;
            if (c3) { int g = atomicAdd(&gcur[b0 + 3], c3); dlt[b0 + 3] = g - lb; }
        }
    }
    __syncthreads();

    for (int i = tid; i < n; i += 256) {
        unsigned k = (unsigned)key[base + i];
        int slot = atomicAdd(&hist[k >> BSHIFT], 1);
        sk[slot] = k;
    }
    __syncthreads();

    for (int i = tid; i < n; i += 256) {
        unsigned k = sk[i];
        int b = (int)(k >> BSHIFT);
        long dest = (long)dlt[b] + i;
        long capend = (long)(b + 1) * BCAP;
        if (dest < capend) part[dest] = k;
        else atomicAdd(&spill_hist[k], 1);
    }
}

// ---------------- phase-2: odeg histogram ----------------
__global__ __launch_bounds__(256)
void odeg_phase2_kernel(const unsigned* __restrict__ part,
                        const int* __restrict__ gcur,
                        int* __restrict__ odeg, int nN) {
    __shared__ int bins[BNODES];
    int tid = threadIdx.x;
    int bucket = blockIdx.x;
    int nodeBase = bucket << BSHIFT;
    for (int b = tid; b < BNODES; b += 256) bins[b] = 0;
    __syncthreads();
    int start = bucket * BCAP;
    int endv = gcur[bucket];
    if (endv > start + BCAP) endv = start + BCAP;
    for (int i = start + tid; i < endv; i += 256)
        atomicAdd(&bins[(int)part[i] - nodeBase], 1);
    __syncthreads();
    for (int b = tid; b < BNODES; b += 256) {
        int node = nodeBase + b;
        if (node < nN && bins[b]) atomicAdd(&odeg[node], bins[b]);
    }
}

// ---------------- per-bucket counting sort ----------------
__global__ __launch_bounds__(256)
void csr_sort_kernel(const unsigned* __restrict__ part,
                     const int* __restrict__ gcur,
                     unsigned* __restrict__ sorted,
                     int* __restrict__ noffs,
                     int* __restrict__ ndeg,
                     int nN) {
    __shared__ int bins[BNODES];
    __shared__ int w0tot;
    int tid = threadIdx.x;
    int bucket = blockIdx.x;
    int nodeBase = bucket << BSHIFT;
    if (tid < BNODES) bins[tid] = 0;
    __syncthreads();

    int start = bucket * BCAP;
    int endv  = gcur[bucket];
    if (endv > start + BCAP) endv = start + BCAP;

    for (int i = start + tid; i < endv; i += 256)
        atomicAdd(&bins[(int)(part[i] >> 24)], 1);
    __syncthreads();

    int lane = tid & 63, wid = tid >> 6;
    int v = 0, x = 0;
    if (tid < BNODES) {
        v = bins[tid];
        x = v;
        #pragma unroll
        for (int off = 1; off < 64; off <<= 1) {
            int t = __shfl_up(x, off, 64);
            if (lane >= off) x += t;
        }
        if (wid == 0 && lane == 63) w0tot = x;
    }
    __syncthreads();
    if (tid < BNODES) {
        int excl = x - v + (wid ? w0tot : 0);
        bins[tid] = excl;
        int node = nodeBase + tid;
        if (node < nN) { noffs[node] = start + excl; ndeg[node] = v; }
    }
    __syncthreads();

    for (int i = start + tid; i < endv; i += 256) {
        unsigned p = part[i];
        int dl = (int)(p >> 24);
        int pos = atomicAdd(&bins[dl], 1);
        sorted[start + pos] = p & 0xFFFFFFu;
    }
}

// ---------------- bf16 helpers ----------------
__device__ __forceinline__ unsigned short f2bf(float x) {
    unsigned u = __float_as_uint(x);
    u += 0x7fffu + ((u >> 16) & 1u);   // round-to-nearest-even
    return (unsigned short)(u >> 16);
}
__device__ __forceinline__ float bflo(unsigned u) { return __uint_as_float(u << 16); }
__device__ __forceinline__ float bfhi(unsigned u) { return __uint_as_float(u & 0xffff0000u); }

// ---------------- cast: sliced prescaled table ----------------
__global__ void cast_sliced_kernel(const float* __restrict__ u_f,
                                   const float* __restrict__ v_f,
                                   const int* __restrict__ odeg,
                                   unsigned short* __restrict__ tbl,
                                   int nN, int nU) {
    long i = (long)blockIdx.x * blockDim.x + threadIdx.x;
    long n4 = (long)nN * 32;
    if (i >= n4) return;
    int node = (int)(i >> 5);
    int q = (int)(i & 31);
    int slice = q >> 2, qi = q & 3;
    float norm = rsqrtf((float)max(odeg[node], 1));
    const float* base = (node < nU) ? (u_f + (size_t)node * DFEAT)
                                    : (v_f + (size_t)(node - nU) * DFEAT);
    float4 v = ((const float4*)base)[q];
    ushort4 o;
    o.x = f2bf(v.x * norm);
    o.y = f2bf(v.y * norm);
    o.z = f2bf(v.z * norm);
    o.w = f2bf(v.w * norm);
    ((ushort4*)tbl)[((size_t)slice * nN + node) * 4 + qi] = o;
}

// ---------------- aggregate: register entry-list, 16 entries/instr ----------
// slice = bid&7 -> pinned XCD; slice table (nN*32B ~ 3.2MB) L2-resident.
// Wave per node: preload sorted[begin+lane]; eg=lane>>2 (16 entry groups),
// sub=lane&3 (uint2 = 4 bf16 feats). x2 unroll = 2 gathers in flight.
__global__ __launch_bounds__(256)
void agg_sorted2_kernel(const unsigned short* __restrict__ tbl,
                        const unsigned* __restrict__ sorted,
                        const int* __restrict__ noffs,
                        const int* __restrict__ ndeg,
                        const int2* __restrict__ ovfD,
                        const int* __restrict__ ovfD_cnt,
                        float* __restrict__ out,
                        int nN) {
    int tid = threadIdx.x;
    int slice  = blockIdx.x & (NSLICE - 1);
    int bucket = blockIdx.x >> 3;
    int nodeBase = bucket << BSHIFT;
    int lane = tid & 63;
    int wid  = tid >> 6;
    int eg   = lane >> 2;    // entry group 0..15
    int sub  = lane & 3;     // uint2 index within 16-feat row

    const uint2* t8 = (const uint2*)(tbl + (size_t)slice * nN * SFEAT);
    int m = *ovfD_cnt;                       // 0 in practice
    if (m > OVFD_CAP) m = OVFD_CAP;

    for (int nl = wid; nl < BNODES; nl += 4) {
        int node = nodeBase + nl;
        if (node >= nN) break;
        int begin = noffs[node];
        int deg   = ndeg[node];
        int cnt   = min(deg, 64);

        unsigned sb = (lane < cnt) ? sorted[begin + lane] : 0u;

        float a0 = 0.f, a1 = 0.f, a2 = 0.f, a3 = 0.f;
        int extra = 0;

        int k = 0;
        for (; k + 32 <= cnt; k += 32) {       // 2 gathers in flight
            unsigned s0 = __shfl(sb, k + eg, 64);
            unsigned s1 = __shfl(sb, k + 16 + eg, 64);
            uint2 w0 = t8[(size_t)s0 * 4 + sub];
            uint2 w1 = t8[(size_t)s1 * 4 + sub];
            a0 += bflo(w0.x); a1 += bfhi(w0.x);
            a2 += bflo(w0.y); a3 += bfhi(w0.y);
            a0 += bflo(w1.x); a1 += bfhi(w1.x);
            a2 += bflo(w1.y); a3 += bfhi(w1.y);
        }
        for (; k < cnt; k += 16) {
            int e = k + eg;
            unsigned s0 = __shfl(sb, e, 64);
            if (e < cnt) {
                uint2 w = t8[(size_t)s0 * 4 + sub];
                a0 += bflo(w.x); a1 += bfhi(w.x);
                a2 += bflo(w.y); a3 += bfhi(w.y);
            }
        }
        for (int e2 = 64 + eg; e2 < deg; e2 += 16) {   // rare deg>64 tail
            unsigned s = sorted[begin + e2];
            uint2 w = t8[(size_t)s * 4 + sub];
            a0 += bflo(w.x); a1 += bfhi(w.x);
            a2 += bflo(w.y); a3 += bfhi(w.y);
        }
        if (m > 0) {                                    // rare partition spill
            for (int j = eg; j < m; j += 16) {
                int2 e = ovfD[j];
                if (e.x == node) {
                    uint2 w = t8[(size_t)e.y * 4 + sub];
                    a0 += bflo(w.x); a1 += bfhi(w.x);
                    a2 += bflo(w.y); a3 += bfhi(w.y);
                    ++extra;
                }
            }
        }

        a0 += __shfl_xor(a0, 4, 64);  a1 += __shfl_xor(a1, 4, 64);
        a2 += __shfl_xor(a2, 4, 64);  a3 += __shfl_xor(a3, 4, 64);
        a0 += __shfl_xor(a0, 8, 64);  a1 += __shfl_xor(a1, 8, 64);
        a2 += __shfl_xor(a2, 8, 64);  a3 += __shfl_xor(a3, 8, 64);
        a0 += __shfl_xor(a0, 16, 64); a1 += __shfl_xor(a1, 16, 64);
        a2 += __shfl_xor(a2, 16, 64); a3 += __shfl_xor(a3, 16, 64);
        a0 += __shfl_xor(a0, 32, 64); a1 += __shfl_xor(a1, 32, 64);
        a2 += __shfl_xor(a2, 32, 64); a3 += __shfl_xor(a3, 32, 64);
        if (m > 0) {
            extra += __shfl_xor(extra, 4, 64);
            extra += __shfl_xor(extra, 8, 64);
            extra += __shfl_xor(extra, 16, 64);
            extra += __shfl_xor(extra, 32, 64);
        }

        if (lane < 4) {
            float inorm = rsqrtf((float)max(deg + extra, 1));
            ((float4*)(out + (size_t)node * DFEAT + slice * SFEAT))[sub] =
                make_float4(a0 * inorm, a1 * inorm, a2 * inorm, a3 * inorm);
        }
    }
}

// ---------------- fallback: round-5 random-atomic build ----------------
__global__ void build_kernel(const int* __restrict__ src,
                             const int* __restrict__ dst,
                             int* __restrict__ ideg,
                             int* __restrict__ odeg,
                             int* __restrict__ slack,
                             int2* __restrict__ ovf2,
                             int* __restrict__ ovf2_cnt,
                             int nE) {
    int t = blockIdx.x * blockDim.x + threadIdx.x;
    long base = (long)t * 4;
    if (base >= nE) return;
    long lim = base + 4 < (long)nE ? base + 4 : (long)nE;
    for (long e = base; e < lim; ++e) {
        int s = src[e], d = dst[e];
        atomicAdd(&odeg[s], 1);
        int p = atomicAdd(&ideg[d], 1);
        if (p < SLACK) {
            slack[(size_t)d * SLACK + p] = s;
        } else {
            int q = atomicAdd(ovf2_cnt, 1);
            if (q < OVF2_CAP) ovf2[q] = make_int2(d, s);
        }
    }
}

__launch_bounds__(256)
__global__ void aggregate_f32_kernel(const float* __restrict__ u_f,
                                     const float* __restrict__ v_f,
                                     const int* __restrict__ slack,
                                     const int* __restrict__ ideg,
                                     const int* __restrict__ odeg,
                                     const int2* __restrict__ ovf2,
                                     const int* __restrict__ ovf2_cnt,
                                     float* __restrict__ out,
                                     int nN, int nU) {
    int lane = threadIdx.x & 63;
    int wid  = threadIdx.x >> 6;
    int node = blockIdx.x * 4 + wid;
    if (node >= nN) return;

    int deg = ideg[node];
    int cnt = min(deg, SLACK);
    int   sb = 0;
    float nb = 0.f;
    if (lane < cnt) {
        sb = slack[(size_t)node * SLACK + lane];
        nb = rsqrtf((float)max(odeg[sb], 1));
    }
    float2 acc = make_float2(0.f, 0.f);
    for (int k = 0; k < cnt; ++k) {
        int   sk = __shfl(sb, k, 64);
        float nk = __shfl(nb, k, 64);
        const float* row = (sk < nU) ? (u_f + (size_t)sk * DFEAT)
                                     : (v_f + (size_t)(sk - nU) * DFEAT);
        float2 v = ((const float2*)row)[lane];
        acc.x += v.x * nk;
        acc.y += v.y * nk;
    }
    if (deg > SLACK) {
        int m = *ovf2_cnt; if (m > OVF2_CAP) m = OVF2_CAP;
        for (int j = 0; j < m; ++j) {
            int2 os = ovf2[j];
            if (os.x == node) {
                int sk = os.y;
                float nk = rsqrtf((float)max(odeg[sk], 1));
                const float* row = (sk < nU) ? (u_f + (size_t)sk * DFEAT)
                                             : (v_f + (size_t)(sk - nU) * DFEAT);
                float2 v = ((const float2*)row)[lane];
                acc.x += v.x * nk;
                acc.y += v.y * nk;
            }
        }
    }
    float inorm = rsqrtf((float)max(deg, 1));
    acc.x *= inorm; acc.y *= inorm;
    ((float2*)(out + (size_t)node * DFEAT))[lane] = acc;
}

extern "C" void kernel_launch(void* const* d_in, const int* in_sizes, int n_in,
                              void* d_out, int out_size, void* d_ws, size_t ws_size,
                              hipStream_t stream) {
    const float* u_f = (const float*)d_in[0];
    const float* v_f = (const float*)d_in[1];
    const int*   src = (const int*)d_in[2];
    const int*   dst = (const int*)d_in[3];
    float* out = (float*)d_out;

    int nU = in_sizes[0] / DFEAT;
    int nV = in_sizes[1] / DFEAT;
    int nN = nU + nV;
    int nE = in_sizes[2];
    int nbuk = (nN + BNODES - 1) >> BSHIFT;

    // ---- new-path workspace layout (ints) ----
    int*  odeg  = (int*)d_ws;
    int*  cnts  = odeg + nN;                 // [1] = ovfD_cnt
    int2* ovfD  = (int2*)(cnts + 8);
    int*  gcurD = (int*)(ovfD + OVFD_CAP);
    int*  gcurS = gcurD + MAXBUK;
    int*  noffs = gcurS + MAXBUK;
    int*  ndeg  = noffs + nN;
    unsigned* sorted = (unsigned*)(ndeg + nN);
    size_t partInts = (size_t)nbuk * BCAP;
    unsigned* partS = sorted + partInts;
    unsigned* partD = partS + partInts;
    unsigned short* tbl = (unsigned short*)partS;   // overlays partS+partD
    size_t fixedInts = (size_t)3 * nN + 8 + 2 * (size_t)OVFD_CAP + 2 * MAXBUK;
    size_t tblInts   = (size_t)nN * (DFEAT / 2);
    size_t tailInts  = (2 * partInts > tblInts) ? 2 * partInts : tblInts;
    size_t needNew   = (fixedInts + partInts + tailInts) * 4;
    bool use_new = (nN <= (MAXBUK << BSHIFT)) && (nN < (1 << 24))
                   && (ws_size >= needNew);

    if (use_new) {
        hipMemsetAsync(d_ws, 0, ((size_t)nN + 8) * sizeof(int), stream);
        int nCh = (nE + CH - 1) / CH;
        init_kernel<<<(nbuk + 255) / 256, 256, 0, stream>>>(gcurD, gcurS, nbuk);
        partition_keys_kernel<<<nCh, 256, 0, stream>>>(src, gcurS, partS, odeg,
                                                       nE, nbuk);
        odeg_phase2_kernel<<<nbuk, 256, 0, stream>>>(partS, gcurS, odeg, nN);
        partition_pairs_kernel<<<nCh, 256, 0, stream>>>(dst, src, gcurD, partD,
                                                        ovfD, cnts + 1, nE, nbuk);
        csr_sort_kernel<<<nbuk, 256, 0, stream>>>(partD, gcurD, sorted,
                                                  noffs, ndeg, nN);
        {   // cast AFTER csr_sort: tbl overwrites partS+partD (both dead)
            long n4 = (long)nN * 32;
            cast_sliced_kernel<<<(int)((n4 + 255) / 256), 256, 0, stream>>>(
                u_f, v_f, odeg, tbl, nN, nU);
        }
        agg_sorted2_kernel<<<nbuk * NSLICE, 256, 0, stream>>>(tbl, sorted, noffs,
                                                              ndeg, ovfD, cnts + 1,
                                                              out, nN);
    } else {
        // ---- fallback: round-5 layout ----
        int*  f_ideg = (int*)d_ws;
        int*  f_odeg = f_ideg + nN;
        int*  f_cnts = f_odeg + nN;          // [0] = ovf2_cnt
        int2* f_ovf2 = (int2*)(f_cnts + 8);
        int*  f_slack = (int*)(f_ovf2 + OVF2_CAP);

        hipMemsetAsync(d_ws, 0, ((size_t)2 * nN + 8) * sizeof(int), stream);
        long nT = ((long)nE + 3) / 4;
        build_kernel<<<(int)((nT + 255) / 256), 256, 0, stream>>>(
            src, dst, f_ideg, f_odeg, f_slack, f_ovf2, f_cnts + 0, nE);
        aggregate_f32_kernel<<<(nN + 3) / 4, 256, 0, stream>>>(
            u_f, v_f, f_slack, f_ideg, f_odeg, f_ovf2, f_cnts + 0, out, nN, nU);
    }
}

// Round 11
// 208.784 us; speedup vs baseline: 1.7312x; 1.4979x over previous
//
#include <hip/hip_runtime.h>

// GCN aggregation — bucketed partition + per-bucket counting sort +
// FULL-ROW register aggregate (R6-proven form, fed by sorted CSR).
//   out = diag(in_deg^-1/2) * A * diag(out_deg^-1/2) * concat(u_f, v_f)
//
// Pipeline:
//   init : gcurD[b]=gcurS[b]=b*BCAP
//   P1s  : partition src keys into 128-node buckets (LDS staged)
//   P2s  : per-bucket LDS histogram -> odeg
//   P1d  : partition edges by dst bucket, PACKED (d_local<<24|src) uint
//   sort : per-bucket counting sort -> sorted[] + noffs/ndeg
//   cast : full-row bf16 table  tbl[node][128] = bf16(node_f * rsqrt(odeg))
//   agg  : wave per dst node (4/block): preload sorted[begin+lane], half-wave
//          row pairing (uint2/lane, 256B row per 32 lanes), k+=4 unroll
//          (2 gathers in flight), 4 shfl_xor combine, fused in-norm.
//          (R6 measured 84us for this exact access pattern; R7-R10 sliced
//           variants all lost to per-node x8 overhead despite L2 residency.)
//
// Fallback (small ws): round-5 slack-CSR random-atomic build + f32 gather.

#define DFEAT 128
#define SLACK 64
#define OVF2_CAP 65536
#define OVFD_CAP 65536
#define BSHIFT 7
#define BNODES 128
#define MAXBUK 1024         // supports nN <= 131072
#define BCAP 4096
#define CH 6144

// ---------------- init ----------------
__global__ void init_kernel(int* __restrict__ gcurD, int* __restrict__ gcurS,
                            int nbuk) {
    int b = blockIdx.x * blockDim.x + threadIdx.x;
    if (b < nbuk) { gcurD[b] = b * BCAP; gcurS[b] = b * BCAP; }
}

// ---------------- partition: (dst,src) pairs, packed flush ----------------
__global__ __launch_bounds__(256)
void partition_pairs_kernel(const int* __restrict__ dst,
                            const int* __restrict__ src,
                            int* __restrict__ gcur,
                            unsigned* __restrict__ part,   // packed uint
                            int2* __restrict__ ovf,
                            int* __restrict__ ovf_cnt,
                            int nE, int nbuk) {
    __shared__ int hist[MAXBUK];
    __shared__ int dlt[MAXBUK];
    __shared__ int wsum[4];
    __shared__ unsigned sk[CH];
    __shared__ unsigned sv[CH];

    int tid = threadIdx.x;
    long base = (long)blockIdx.x * CH;
    int n = (int)(((long)nE - base) < CH ? ((long)nE - base) : CH);
    if (n <= 0) return;

    for (int b = tid; b < nbuk; b += 256) hist[b] = 0;
    __syncthreads();
    for (int i = tid; i < n; i += 256)
        atomicAdd(&hist[((unsigned)dst[base + i]) >> BSHIFT], 1);
    __syncthreads();

    int b0 = tid * 4;
    int c0 = 0, c1 = 0, c2 = 0, c3 = 0, sum = 0;
    if (b0 < nbuk) {
        c0 = hist[b0];
        c1 = (b0 + 1 < nbuk) ? hist[b0 + 1] : 0;
        c2 = (b0 + 2 < nbuk) ? hist[b0 + 2] : 0;
        c3 = (b0 + 3 < nbuk) ? hist[b0 + 3] : 0;
        sum = c0 + c1 + c2 + c3;
    }
    int lane = tid & 63, wid = tid >> 6;
    int x = sum;
    #pragma unroll
    for (int off = 1; off < 64; off <<= 1) {
        int t = __shfl_up(x, off, 64);
        if (lane >= off) x += t;
    }
    if (lane == 63) wsum[wid] = x;
    __syncthreads();
    int wpre = 0;
    for (int w = 0; w < wid; ++w) wpre += wsum[w];
    int excl = wpre + x - sum;
    __syncthreads();
    if (b0 < nbuk) {
        int lb = excl;
        hist[b0] = lb;
        if (c0) { int g = atomicAdd(&gcur[b0], c0); dlt[b0] = g - lb; }
        lb += c0;
        if (b0 + 1 < nbuk) {
            hist[b0 + 1] = lb;
            if (c1) { int g = atomicAdd(&gcur[b0 + 1], c1); dlt[b0 + 1] = g - lb; }
            lb += c1;
        }
        if (b0 + 2 < nbuk) {
            hist[b0 + 2] = lb;
            if (c2) { int g = atomicAdd(&gcur[b0 + 2], c2); dlt[b0 + 2] = g - lb; }
            lb += c2;
        }
        if (b0 + 3 < nbuk) {
            hist[b0 + 3] = lb;
            if (c3) { int g = atomicAdd(&gcur[b0 + 3], c3); dlt[b0 + 3] = g - lb; }
        }
    }
    __syncthreads();

    for (int i = tid; i < n; i += 256) {
        unsigned d = (unsigned)dst[base + i];
        unsigned s = (unsigned)src[base + i];
        int slot = atomicAdd(&hist[d >> BSHIFT], 1);
        sk[slot] = d; sv[slot] = s;
    }
    __syncthreads();

    for (int i = tid; i < n; i += 256) {
        unsigned d = sk[i], s = sv[i];
        int b = (int)(d >> BSHIFT);
        long dest = (long)dlt[b] + i;
        long capend = (long)(b + 1) * BCAP;
        if (dest < capend) {
            part[dest] = ((d & (BNODES - 1)) << 24) | s;
        } else {
            int q = atomicAdd(ovf_cnt, 1);
            if (q < OVFD_CAP) ovf[q] = make_int2((int)d, (int)s);
        }
    }
}

// ---------------- partition: src keys only ----------------
__global__ __launch_bounds__(256)
void partition_keys_kernel(const int* __restrict__ key,
                           int* __restrict__ gcur,
                           unsigned* __restrict__ part,
                           int* __restrict__ spill_hist,  // odeg; spills add here
                           int nE, int nbuk) {
    __shared__ int hist[MAXBUK];
    __shared__ int dlt[MAXBUK];
    __shared__ int wsum[4];
    __shared__ unsigned sk[CH];

    int tid = threadIdx.x;
    long base = (long)blockIdx.x * CH;
    int n = (int)(((long)nE - base) < CH ? ((long)nE - base) : CH);
    if (n <= 0) return;

    for (int b = tid; b < nbuk; b += 256) hist[b] = 0;
    __syncthreads();
    for (int i = tid; i < n; i += 256)
        atomicAdd(&hist[((unsigned)key[base + i]) >> BSHIFT], 1);
    __syncthreads();

    int b0 = tid * 4;
    int c0 = 0, c1 = 0, c2 = 0, c3 = 0, sum = 0;
    if (b0 < nbuk) {
        c0 = hist[b0];
        c1 = (b0 + 1 < nbuk) ? hist[b0 + 1] : 0;
        c2 = (b0 + 2 < nbuk) ? hist[b0 + 2] : 0;
        c3 = (b0 + 3 < nbuk) ? hist[b0 + 3] : 0;
        sum = c0 + c1 + c2 + c3;
    }
    int lane = tid & 63, wid = tid >> 6;
    int x = sum;
    #pragma unroll
    for (int off = 1; off < 64; off <<= 1) {
        int t = __shfl_up(x, off, 64);
        if (lane >= off) x += t;
    }
    if (lane == 63) wsum[wid] = x;
    __syncthreads();
    int wpre = 0;
    for (int w = 0; w < wid; ++w) wpre += wsum[w];
    int excl = wpre + x - sum;
    __syncthreads();
    if (b0 < nbuk) {
        int lb = excl;
        hist[b0] = lb;
        if (c0) { int g = atomicAdd(&gcur[b0], c0); dlt[b0] = g - lb; }
        lb += c0;
        if (b0 + 1 < nbuk) {
            hist[b0 + 1] = lb;
            if (c1) { int g = atomicAdd(&gcur[b0 + 1], c1); dlt[b0 + 1] = g - lb; }
            lb += c1;
        }
        if (b0 + 2 < nbuk) {
            hist[b0 + 2] = lb;
            if (c2) { int g = atomicAdd(&gcur[b0 + 2], c2); dlt[b0 + 2] = g - lb; }
            lb += c2;
        }
        if (b0 + 3 < nbuk) {
            hist[b0 + 3] = lb;
            if (c3) { int g = atomicAdd(&gcur[b0 + 3], c3); dlt[b0 + 3] = g - lb; }
        }
    }
    __syncthreads();

    for (int i = tid; i < n; i += 256) {
        unsigned k = (unsigned)key[base + i];
        int slot = atomicAdd(&hist[k >> BSHIFT], 1);
        sk[slot] = k;
    }
    __syncthreads();

    for (int i = tid; i < n; i += 256) {
        unsigned k = sk[i];
        int b = (int)(k >> BSHIFT);
        long dest = (long)dlt[b] + i;
        long capend = (long)(b + 1) * BCAP;
        if (dest < capend) part[dest] = k;
        else atomicAdd(&spill_hist[k], 1);
    }
}

// ---------------- phase-2: odeg histogram ----------------
__global__ __launch_bounds__(256)
void odeg_phase2_kernel(const unsigned* __restrict__ part,
                        const int* __restrict__ gcur,
                        int* __restrict__ odeg, int nN) {
    __shared__ int bins[BNODES];
    int tid = threadIdx.x;
    int bucket = blockIdx.x;
    int nodeBase = bucket << BSHIFT;
    for (int b = tid; b < BNODES; b += 256) bins[b] = 0;
    __syncthreads();
    int start = bucket * BCAP;
    int endv = gcur[bucket];
    if (endv > start + BCAP) endv = start + BCAP;
    for (int i = start + tid; i < endv; i += 256)
        atomicAdd(&bins[(int)part[i] - nodeBase], 1);
    __syncthreads();
    for (int b = tid; b < BNODES; b += 256) {
        int node = nodeBase + b;
        if (node < nN && bins[b]) atomicAdd(&odeg[node], bins[b]);
    }
}

// ---------------- per-bucket counting sort ----------------
__global__ __launch_bounds__(256)
void csr_sort_kernel(const unsigned* __restrict__ part,
                     const int* __restrict__ gcur,
                     unsigned* __restrict__ sorted,
                     int* __restrict__ noffs,
                     int* __restrict__ ndeg,
                     int nN) {
    __shared__ int bins[BNODES];
    __shared__ int w0tot;
    int tid = threadIdx.x;
    int bucket = blockIdx.x;
    int nodeBase = bucket << BSHIFT;
    if (tid < BNODES) bins[tid] = 0;
    __syncthreads();

    int start = bucket * BCAP;
    int endv  = gcur[bucket];
    if (endv > start + BCAP) endv = start + BCAP;

    for (int i = start + tid; i < endv; i += 256)
        atomicAdd(&bins[(int)(part[i] >> 24)], 1);
    __syncthreads();

    int lane = tid & 63, wid = tid >> 6;
    int v = 0, x = 0;
    if (tid < BNODES) {
        v = bins[tid];
        x = v;
        #pragma unroll
        for (int off = 1; off < 64; off <<= 1) {
            int t = __shfl_up(x, off, 64);
            if (lane >= off) x += t;
        }
        if (wid == 0 && lane == 63) w0tot = x;
    }
    __syncthreads();
    if (tid < BNODES) {
        int excl = x - v + (wid ? w0tot : 0);
        bins[tid] = excl;
        int node = nodeBase + tid;
        if (node < nN) { noffs[node] = start + excl; ndeg[node] = v; }
    }
    __syncthreads();

    for (int i = start + tid; i < endv; i += 256) {
        unsigned p = part[i];
        int dl = (int)(p >> 24);
        int pos = atomicAdd(&bins[dl], 1);
        sorted[start + pos] = p & 0xFFFFFFu;
    }
}

// ---------------- bf16 helpers ----------------
__device__ __forceinline__ unsigned short f2bf(float x) {
    unsigned u = __float_as_uint(x);
    u += 0x7fffu + ((u >> 16) & 1u);   // round-to-nearest-even
    return (unsigned short)(u >> 16);
}
__device__ __forceinline__ float bflo(unsigned u) { return __uint_as_float(u << 16); }
__device__ __forceinline__ float bfhi(unsigned u) { return __uint_as_float(u & 0xffff0000u); }

// ---------------- cast: full-row prescaled table ----------------
// tbl[node][128] bf16 = node_f * rsqrt(max(odeg,1)); one thread per float4.
__global__ void cast_kernel(const float* __restrict__ u_f,
                            const float* __restrict__ v_f,
                            const int* __restrict__ odeg,
                            unsigned short* __restrict__ tbl,
                            int nN, int nU) {
    long i = (long)blockIdx.x * blockDim.x + threadIdx.x;
    long n4 = (long)nN * 32;
    if (i >= n4) return;
    int node = (int)(i >> 5);
    float norm = rsqrtf((float)max(odeg[node], 1));
    const float* base = (node < nU) ? (u_f + (size_t)node * DFEAT)
                                    : (v_f + (size_t)(node - nU) * DFEAT);
    float4 v = ((const float4*)base)[i & 31];
    ushort4 o;
    o.x = f2bf(v.x * norm);
    o.y = f2bf(v.y * norm);
    o.z = f2bf(v.z * norm);
    o.w = f2bf(v.w * norm);
    ((ushort4*)tbl)[i] = o;
}

// ---------------- aggregate: full-row, wave per node (R6 form) ----------------
// Half-wave pairing: lanes 0-31 row k+0, lanes 32-63 row k+1; uint2/lane.
// k+=4 unroll keeps 2 row-gathers in flight per half.
__global__ __launch_bounds__(256)
void agg_full_kernel(const unsigned short* __restrict__ tbl,
                     const unsigned* __restrict__ sorted,
                     const int* __restrict__ noffs,
                     const int* __restrict__ ndeg,
                     const int2* __restrict__ ovfD,
                     const int* __restrict__ ovfD_cnt,
                     float* __restrict__ out,
                     int nN) {
    int lane = threadIdx.x & 63;
    int half = lane >> 5;
    int l32  = lane & 31;
    int wid  = threadIdx.x >> 6;
    int node = blockIdx.x * 4 + wid;
    if (node >= nN) return;

    int begin = noffs[node];
    int deg   = ndeg[node];
    int cnt   = min(deg, 64);

    unsigned sb = (lane < cnt) ? sorted[begin + lane] : 0u;

    float ax = 0.f, ay = 0.f, az = 0.f, aw = 0.f;
    const uint2* t = (const uint2*)tbl;   // 32 uint2 per row

    int k = 0;
    for (; k + 4 <= cnt; k += 4) {
        unsigned s0 = __shfl(sb, k + half, 64);
        unsigned s1 = __shfl(sb, k + 2 + half, 64);
        uint2 w0 = t[(size_t)s0 * 32 + l32];
        uint2 w1 = t[(size_t)s1 * 32 + l32];
        ax += bflo(w0.x); ay += bfhi(w0.x);
        az += bflo(w0.y); aw += bfhi(w0.y);
        ax += bflo(w1.x); ay += bfhi(w1.x);
        az += bflo(w1.y); aw += bfhi(w1.y);
    }
    if (k + 2 <= cnt) {
        unsigned s0 = __shfl(sb, k + half, 64);
        uint2 w0 = t[(size_t)s0 * 32 + l32];
        ax += bflo(w0.x); ay += bfhi(w0.x);
        az += bflo(w0.y); aw += bfhi(w0.y);
        k += 2;
    }
    if (k < cnt) {                        // odd tail: half 0 only
        unsigned s0 = __shfl(sb, k, 64);
        uint2 w = t[(size_t)s0 * 32 + l32];
        if (!half) {
            ax += bflo(w.x); ay += bfhi(w.x);
            az += bflo(w.y); aw += bfhi(w.y);
        }
    }
    for (int e = 64 + half; e < deg; e += 2) {   // rare deg>64 tail
        unsigned s = sorted[begin + e];
        uint2 w = t[(size_t)s * 32 + l32];
        ax += bflo(w.x); ay += bfhi(w.x);
        az += bflo(w.y); aw += bfhi(w.y);
    }
    int extra = 0;
    int m = *ovfD_cnt;                    // 0 in practice
    if (m > 0) {
        if (m > OVFD_CAP) m = OVFD_CAP;
        for (int j = half; j < m; j += 2) {
            int2 e = ovfD[j];
            if (e.x == node) {
                uint2 w = t[(size_t)e.y * 32 + l32];
                ax += bflo(w.x); ay += bfhi(w.x);
                az += bflo(w.y); aw += bfhi(w.y);
                ++extra;
            }
        }
        extra += __shfl_xor(extra, 32, 64);
    }

    ax += __shfl_xor(ax, 32, 64);
    ay += __shfl_xor(ay, 32, 64);
    az += __shfl_xor(az, 32, 64);
    aw += __shfl_xor(aw, 32, 64);

    if (!half) {
        float inorm = rsqrtf((float)max(deg + extra, 1));
        ((float4*)(out + (size_t)node * DFEAT))[l32] =
            make_float4(ax * inorm, ay * inorm, az * inorm, aw * inorm);
    }
}

// ---------------- fallback: round-5 random-atomic build ----------------
__global__ void build_kernel(const int* __restrict__ src,
                             const int* __restrict__ dst,
                             int* __restrict__ ideg,
                             int* __restrict__ odeg,
                             int* __restrict__ slack,
                             int2* __restrict__ ovf2,
                             int* __restrict__ ovf2_cnt,
                             int nE) {
    int t = blockIdx.x * blockDim.x + threadIdx.x;
    long base = (long)t * 4;
    if (base >= nE) return;
    long lim = base + 4 < (long)nE ? base + 4 : (long)nE;
    for (long e = base; e < lim; ++e) {
        int s = src[e], d = dst[e];
        atomicAdd(&odeg[s], 1);
        int p = atomicAdd(&ideg[d], 1);
        if (p < SLACK) {
            slack[(size_t)d * SLACK + p] = s;
        } else {
            int q = atomicAdd(ovf2_cnt, 1);
            if (q < OVF2_CAP) ovf2[q] = make_int2(d, s);
        }
    }
}

__launch_bounds__(256)
__global__ void aggregate_f32_kernel(const float* __restrict__ u_f,
                                     const float* __restrict__ v_f,
                                     const int* __restrict__ slack,
                                     const int* __restrict__ ideg,
                                     const int* __restrict__ odeg,
                                     const int2* __restrict__ ovf2,
                                     const int* __restrict__ ovf2_cnt,
                                     float* __restrict__ out,
                                     int nN, int nU) {
    int lane = threadIdx.x & 63;
    int wid  = threadIdx.x >> 6;
    int node = blockIdx.x * 4 + wid;
    if (node >= nN) return;

    int deg = ideg[node];
    int cnt = min(deg, SLACK);
    int   sb = 0;
    float nb = 0.f;
    if (lane < cnt) {
        sb = slack[(size_t)node * SLACK + lane];
        nb = rsqrtf((float)max(odeg[sb], 1));
    }
    float2 acc = make_float2(0.f, 0.f);
    for (int k = 0; k < cnt; ++k) {
        int   sk = __shfl(sb, k, 64);
        float nk = __shfl(nb, k, 64);
        const float* row = (sk < nU) ? (u_f + (size_t)sk * DFEAT)
                                     : (v_f + (size_t)(sk - nU) * DFEAT);
        float2 v = ((const float2*)row)[lane];
        acc.x += v.x * nk;
        acc.y += v.y * nk;
    }
    if (deg > SLACK) {
        int m = *ovf2_cnt; if (m > OVF2_CAP) m = OVF2_CAP;
        for (int j = 0; j < m; ++j) {
            int2 os = ovf2[j];
            if (os.x == node) {
                int sk = os.y;
                float nk = rsqrtf((float)max(odeg[sk], 1));
                const float* row = (sk < nU) ? (u_f + (size_t)sk * DFEAT)
                                             : (v_f + (size_t)(sk - nU) * DFEAT);
                float2 v = ((const float2*)row)[lane];
                acc.x += v.x * nk;
                acc.y += v.y * nk;
            }
        }
    }
    float inorm = rsqrtf((float)max(deg, 1));
    acc.x *= inorm; acc.y *= inorm;
    ((float2*)(out + (size_t)node * DFEAT))[lane] = acc;
}

extern "C" void kernel_launch(void* const* d_in, const int* in_sizes, int n_in,
                              void* d_out, int out_size, void* d_ws, size_t ws_size,
                              hipStream_t stream) {
    const float* u_f = (const float*)d_in[0];
    const float* v_f = (const float*)d_in[1];
    const int*   src = (const int*)d_in[2];
    const int*   dst = (const int*)d_in[3];
    float* out = (float*)d_out;

    int nU = in_sizes[0] / DFEAT;
    int nV = in_sizes[1] / DFEAT;
    int nN = nU + nV;
    int nE = in_sizes[2];
    int nbuk = (nN + BNODES - 1) >> BSHIFT;

    // ---- new-path workspace layout (ints) ----
    int*  odeg  = (int*)d_ws;
    int*  cnts  = odeg + nN;                 // [1] = ovfD_cnt
    int2* ovfD  = (int2*)(cnts + 8);
    int*  gcurD = (int*)(ovfD + OVFD_CAP);
    int*  gcurS = gcurD + MAXBUK;
    int*  noffs = gcurS + MAXBUK;
    int*  ndeg  = noffs + nN;
    unsigned* sorted = (unsigned*)(ndeg + nN);
    size_t partInts = (size_t)nbuk * BCAP;
    unsigned* partS = sorted + partInts;
    unsigned* partD = partS + partInts;
    unsigned short* tbl = (unsigned short*)partS;   // overlays partS+partD
    size_t fixedInts = (size_t)3 * nN + 8 + 2 * (size_t)OVFD_CAP + 2 * MAXBUK;
    size_t tblInts   = (size_t)nN * (DFEAT / 2);
    size_t tailInts  = (2 * partInts > tblInts) ? 2 * partInts : tblInts;
    size_t needNew   = (fixedInts + partInts + tailInts) * 4;
    bool use_new = (nN <= (MAXBUK << BSHIFT)) && (nN < (1 << 24))
                   && (ws_size >= needNew);

    if (use_new) {
        hipMemsetAsync(d_ws, 0, ((size_t)nN + 8) * sizeof(int), stream);
        int nCh = (nE + CH - 1) / CH;
        init_kernel<<<(nbuk + 255) / 256, 256, 0, stream>>>(gcurD, gcurS, nbuk);
        partition_keys_kernel<<<nCh, 256, 0, stream>>>(src, gcurS, partS, odeg,
                                                       nE, nbuk);
        odeg_phase2_kernel<<<nbuk, 256, 0, stream>>>(partS, gcurS, odeg, nN);
        partition_pairs_kernel<<<nCh, 256, 0, stream>>>(dst, src, gcurD, partD,
                                                        ovfD, cnts + 1, nE, nbuk);
        csr_sort_kernel<<<nbuk, 256, 0, stream>>>(partD, gcurD, sorted,
                                                  noffs, ndeg, nN);
        {   // cast AFTER csr_sort: tbl overwrites partS+partD (both dead)
            long n4 = (long)nN * 32;
            cast_kernel<<<(int)((n4 + 255) / 256), 256, 0, stream>>>(
                u_f, v_f, odeg, tbl, nN, nU);
        }
        agg_full_kernel<<<(nN + 3) / 4, 256, 0, stream>>>(tbl, sorted, noffs,
                                                          ndeg, ovfD, cnts + 1,
                                                          out, nN);
    } else {
        // ---- fallback: round-5 layout ----
        int*  f_ideg = (int*)d_ws;
        int*  f_odeg = f_ideg + nN;
        int*  f_cnts = f_odeg + nN;          // [0] = ovf2_cnt
        int2* f_ovf2 = (int2*)(f_cnts + 8);
        int*  f_slack = (int*)(f_ovf2 + OVF2_CAP);

        hipMemsetAsync(d_ws, 0, ((size_t)2 * nN + 8) * sizeof(int), stream);
        long nT = ((long)nE + 3) / 4;
        build_kernel<<<(int)((nT + 255) / 256), 256, 0, stream>>>(
            src, dst, f_ideg, f_odeg, f_slack, f_ovf2, f_cnts + 0, nE);
        aggregate_f32_kernel<<<(nN + 3) / 4, 256, 0, stream>>>(
            u_f, v_f, f_slack, f_ideg, f_odeg, f_ovf2, f_cnts + 0, out, nN, nU);
    }
}

// Round 12
// 208.751 us; speedup vs baseline: 1.7315x; 1.0002x over previous
//
#include <hip/hip_runtime.h>

// GCN aggregation — bucketed partition + fused (LDS-sort + full-row gather)
// aggregate, bf16 prescaled table.
//   out = diag(in_deg^-1/2) * A * diag(out_deg^-1/2) * concat(u_f, v_f)
//
// Pipeline:
//   init : gcurD[b]=gcurS[b]=b*BCAP
//   P1s  : partition src keys into 128-node buckets (LDS staged)
//   P2s  : per-bucket LDS histogram -> odeg
//   P1d  : partition edges by dst bucket, PACKED (d_local<<24|src) uint
//   cast : full-row bf16 table  tbl[node][128] = bf16(node_f * rsqrt(odeg))
//          (tbl overlays partS, dead after P2s)
//   agg  : block per bucket (512 thr): LDS counting-sort of the bucket's packed
//          pairs (once), then wave-per-node full-row gather: quarter-wave
//          pairing (uint4/lane = 8 bf16, 16 lanes/row), entry index via
//          same-address LDS broadcast, k+=8 unroll (2 loads in flight),
//          2-step shfl_xor reduce, fused in-norm.
//
// Fallback (small ws): round-5 slack-CSR random-atomic build + f32 gather.

#define DFEAT 128
#define SLACK 64
#define OVF2_CAP 65536
#define OVFD_CAP 65536
#define BSHIFT 7
#define BNODES 128
#define MAXBUK 1024         // supports nN <= 131072
#define BCAP 4096
#define CH 6144

// ---------------- init ----------------
__global__ void init_kernel(int* __restrict__ gcurD, int* __restrict__ gcurS,
                            int nbuk) {
    int b = blockIdx.x * blockDim.x + threadIdx.x;
    if (b < nbuk) { gcurD[b] = b * BCAP; gcurS[b] = b * BCAP; }
}

// ---------------- partition: (dst,src) pairs, packed flush ----------------
__global__ __launch_bounds__(256)
void partition_pairs_kernel(const int* __restrict__ dst,
                            const int* __restrict__ src,
                            int* __restrict__ gcur,
                            unsigned* __restrict__ part,   // packed uint
                            int2* __restrict__ ovf,
                            int* __restrict__ ovf_cnt,
                            int nE, int nbuk) {
    __shared__ int hist[MAXBUK];
    __shared__ int dlt[MAXBUK];
    __shared__ int wsum[4];
    __shared__ unsigned sk[CH];
    __shared__ unsigned sv[CH];

    int tid = threadIdx.x;
    long base = (long)blockIdx.x * CH;
    int n = (int)(((long)nE - base) < CH ? ((long)nE - base) : CH);
    if (n <= 0) return;

    for (int b = tid; b < nbuk; b += 256) hist[b] = 0;
    __syncthreads();
    for (int i = tid; i < n; i += 256)
        atomicAdd(&hist[((unsigned)dst[base + i]) >> BSHIFT], 1);
    __syncthreads();

    int b0 = tid * 4;
    int c0 = 0, c1 = 0, c2 = 0, c3 = 0, sum = 0;
    if (b0 < nbuk) {
        c0 = hist[b0];
        c1 = (b0 + 1 < nbuk) ? hist[b0 + 1] : 0;
        c2 = (b0 + 2 < nbuk) ? hist[b0 + 2] : 0;
        c3 = (b0 + 3 < nbuk) ? hist[b0 + 3] : 0;
        sum = c0 + c1 + c2 + c3;
    }
    int lane = tid & 63, wid = tid >> 6;
    int x = sum;
    #pragma unroll
    for (int off = 1; off < 64; off <<= 1) {
        int t = __shfl_up(x, off, 64);
        if (lane >= off) x += t;
    }
    if (lane == 63) wsum[wid] = x;
    __syncthreads();
    int wpre = 0;
    for (int w = 0; w < wid; ++w) wpre += wsum[w];
    int excl = wpre + x - sum;
    __syncthreads();
    if (b0 < nbuk) {
        int lb = excl;
        hist[b0] = lb;
        if (c0) { int g = atomicAdd(&gcur[b0], c0); dlt[b0] = g - lb; }
        lb += c0;
        if (b0 + 1 < nbuk) {
            hist[b0 + 1] = lb;
            if (c1) { int g = atomicAdd(&gcur[b0 + 1], c1); dlt[b0 + 1] = g - lb; }
            lb += c1;
        }
        if (b0 + 2 < nbuk) {
            hist[b0 + 2] = lb;
            if (c2) { int g = atomicAdd(&gcur[b0 + 2], c2); dlt[b0 + 2] = g - lb; }
            lb += c2;
        }
        if (b0 + 3 < nbuk) {
            hist[b0 + 3] = lb;
            if (c3) { int g = atomicAdd(&gcur[b0 + 3], c3); dlt[b0 + 3] = g - lb; }
        }
    }
    __syncthreads();

    for (int i = tid; i < n; i += 256) {
        unsigned d = (unsigned)dst[base + i];
        unsigned s = (unsigned)src[base + i];
        int slot = atomicAdd(&hist[d >> BSHIFT], 1);
        sk[slot] = d; sv[slot] = s;
    }
    __syncthreads();

    for (int i = tid; i < n; i += 256) {
        unsigned d = sk[i], s = sv[i];
        int b = (int)(d >> BSHIFT);
        long dest = (long)dlt[b] + i;
        long capend = (long)(b + 1) * BCAP;
        if (dest < capend) {
            part[dest] = ((d & (BNODES - 1)) << 24) | s;
        } else {
            int q = atomicAdd(ovf_cnt, 1);
            if (q < OVFD_CAP) ovf[q] = make_int2((int)d, (int)s);
        }
    }
}

// ---------------- partition: src keys only ----------------
__global__ __launch_bounds__(256)
void partition_keys_kernel(const int* __restrict__ key,
                           int* __restrict__ gcur,
                           unsigned* __restrict__ part,
                           int* __restrict__ spill_hist,  // odeg; spills add here
                           int nE, int nbuk) {
    __shared__ int hist[MAXBUK];
    __shared__ int dlt[MAXBUK];
    __shared__ int wsum[4];
    __shared__ unsigned sk[CH];

    int tid = threadIdx.x;
    long base = (long)blockIdx.x * CH;
    int n = (int)(((long)nE - base) < CH ? ((long)nE - base) : CH);
    if (n <= 0) return;

    for (int b = tid; b < nbuk; b += 256) hist[b] = 0;
    __syncthreads();
    for (int i = tid; i < n; i += 256)
        atomicAdd(&hist[((unsigned)key[base + i]) >> BSHIFT], 1);
    __syncthreads();

    int b0 = tid * 4;
    int c0 = 0, c1 = 0, c2 = 0, c3 = 0, sum = 0;
    if (b0 < nbuk) {
        c0 = hist[b0];
        c1 = (b0 + 1 < nbuk) ? hist[b0 + 1] : 0;
        c2 = (b0 + 2 < nbuk) ? hist[b0 + 2] : 0;
        c3 = (b0 + 3 < nbuk) ? hist[b0 + 3] : 0;
        sum = c0 + c1 + c2 + c3;
    }
    int lane = tid & 63, wid = tid >> 6;
    int x = sum;
    #pragma unroll
    for (int off = 1; off < 64; off <<= 1) {
        int t = __shfl_up(x, off, 64);
        if (lane >= off) x += t;
    }
    if (lane == 63) wsum[wid] = x;
    __syncthreads();
    int wpre = 0;
    for (int w = 0; w < wid; ++w) wpre += wsum[w];
    int excl = wpre + x - sum;
    __syncthreads();
    if (b0 < nbuk) {
        int lb = excl;
        hist[b0] = lb;
        if (c0) { int g = atomicAdd(&gcur[b0], c0); dlt[b0] = g - lb; }
        lb += c0;
        if (b0 + 1 < nbuk) {
            hist[b0 + 1] = lb;
            if (c1) { int g = atomicAdd(&gcur[b0 + 1], c1); dlt[b0 + 1] = g - lb; }
            lb += c1;
        }
        if (b0 + 2 < nbuk) {
            hist[b0 + 2] = lb;
            if (c2) { int g = atomicAdd(&gcur[b0 + 2], c2); dlt[b0 + 2] = g - lb; }
            lb += c2;
        }
        if (b0 + 3 < nbuk) {
            hist[b0 + 3] = lb;
            if (c3) { int g = atomicAdd(&gcur[b0 + 3], c3); dlt[b0 + 3] = g - lb; }
        }
    }
    __syncthreads();

    for (int i = tid; i < n; i += 256) {
        unsigned k = (unsigned)key[base + i];
        int slot = atomicAdd(&hist[k >> BSHIFT], 1);
        sk[slot] = k;
    }
    __syncthreads();

    for (int i = tid; i < n; i += 256) {
        unsigned k = sk[i];
        int b = (int)(k >> BSHIFT);
        long dest = (long)dlt[b] + i;
        long capend = (long)(b + 1) * BCAP;
        if (dest < capend) part[dest] = k;
        else atomicAdd(&spill_hist[k], 1);
    }
}

// ---------------- phase-2: odeg histogram ----------------
__global__ __launch_bounds__(256)
void odeg_phase2_kernel(const unsigned* __restrict__ part,
                        const int* __restrict__ gcur,
                        int* __restrict__ odeg, int nN) {
    __shared__ int bins[BNODES];
    int tid = threadIdx.x;
    int bucket = blockIdx.x;
    int nodeBase = bucket << BSHIFT;
    for (int b = tid; b < BNODES; b += 256) bins[b] = 0;
    __syncthreads();
    int start = bucket * BCAP;
    int endv = gcur[bucket];
    if (endv > start + BCAP) endv = start + BCAP;
    for (int i = start + tid; i < endv; i += 256)
        atomicAdd(&bins[(int)part[i] - nodeBase], 1);
    __syncthreads();
    for (int b = tid; b < BNODES; b += 256) {
        int node = nodeBase + b;
        if (node < nN && bins[b]) atomicAdd(&odeg[node], bins[b]);
    }
}

// ---------------- bf16 helpers ----------------
__device__ __forceinline__ unsigned short f2bf(float x) {
    unsigned u = __float_as_uint(x);
    u += 0x7fffu + ((u >> 16) & 1u);   // round-to-nearest-even
    return (unsigned short)(u >> 16);
}
__device__ __forceinline__ float bflo(unsigned u) { return __uint_as_float(u << 16); }
__device__ __forceinline__ float bfhi(unsigned u) { return __uint_as_float(u & 0xffff0000u); }

// ---------------- cast: full-row prescaled table ----------------
__global__ void cast_kernel(const float* __restrict__ u_f,
                            const float* __restrict__ v_f,
                            const int* __restrict__ odeg,
                            unsigned short* __restrict__ tbl,
                            int nN, int nU) {
    long i = (long)blockIdx.x * blockDim.x + threadIdx.x;
    long n4 = (long)nN * 32;
    if (i >= n4) return;
    int node = (int)(i >> 5);
    float norm = rsqrtf((float)max(odeg[node], 1));
    const float* base = (node < nU) ? (u_f + (size_t)node * DFEAT)
                                    : (v_f + (size_t)(node - nU) * DFEAT);
    float4 v = ((const float4*)base)[i & 31];
    ushort4 o;
    o.x = f2bf(v.x * norm);
    o.y = f2bf(v.y * norm);
    o.z = f2bf(v.z * norm);
    o.w = f2bf(v.w * norm);
    ((ushort4*)tbl)[i] = o;
}

// ---------------- aggregate: fused LDS sort + full-row gather ----------------
// Block per bucket, 512 threads (8 waves). Phase A: LDS counting sort of the
// bucket's packed pairs. Phase B: wave per node (16 nodes/wave): quarter-wave
// pairing, uint4/lane (8 bf16), LDS-broadcast entry index, k+=8 unroll.
__global__ __launch_bounds__(512)
void agg_fused_kernel(const unsigned short* __restrict__ tbl,
                      const unsigned* __restrict__ part,
                      const int* __restrict__ gcur,
                      const int2* __restrict__ ovfD,
                      const int* __restrict__ ovfD_cnt,
                      float* __restrict__ out,
                      int nN) {
    __shared__ unsigned sl[BCAP];
    __shared__ int bins[BNODES];    // counts -> noffs
    __shared__ int curs[BNODES];    // running cursor -> end offsets
    __shared__ int w0tot_s;

    int tid = threadIdx.x;
    int bucket = blockIdx.x;
    int nodeBase = bucket << BSHIFT;
    int lane = tid & 63;
    int wv   = tid >> 6;           // 0..7

    if (tid < BNODES) bins[tid] = 0;
    __syncthreads();

    int start = bucket * BCAP;
    int endv  = gcur[bucket];
    if (endv > start + BCAP) endv = start + BCAP;
    int n = endv - start;

    // Phase A1: histogram
    for (int i = tid; i < n; i += 512)
        atomicAdd(&bins[part[start + i] >> 24], 1);
    __syncthreads();

    // Phase A2: exclusive scan of 128 bins (waves 0,1)
    int v = 0, x = 0;
    if (tid < BNODES) {
        v = bins[tid];
        x = v;
        #pragma unroll
        for (int off = 1; off < 64; off <<= 1) {
            int t = __shfl_up(x, off, 64);
            if (lane >= off) x += t;
        }
        if (tid == 63) w0tot_s = x;
    }
    __syncthreads();
    if (tid < BNODES) {
        int excl = x - v + ((tid >= 64) ? w0tot_s : 0);
        bins[tid] = excl;
        curs[tid] = excl;
    }
    __syncthreads();

    // Phase A3: scatter into compact LDS list
    for (int i = tid; i < n; i += 512) {
        unsigned p = part[start + i];
        int dl = (int)(p >> 24);
        int pos = atomicAdd(&curs[dl], 1);
        sl[pos] = p & 0xFFFFFFu;
    }
    __syncthreads();

    // Phase B: aggregate. quarter q = lane>>4, l16 = lane&15.
    int q = lane >> 4;
    int l16 = lane & 15;
    const uint4* t = (const uint4*)tbl;   // 16 uint4 per 256B row
    int m = *ovfD_cnt;                    // 0 in practice
    if (m > OVFD_CAP) m = OVFD_CAP;

    for (int nl = wv; nl < BNODES; nl += 8) {
        int node = nodeBase + nl;
        if (node >= nN) continue;
        int beg  = bins[nl];
        int endn = curs[nl];
        int deg  = endn - beg;

        float a0 = 0.f, a1 = 0.f, a2 = 0.f, a3 = 0.f;
        float a4 = 0.f, a5 = 0.f, a6 = 0.f, a7 = 0.f;

        int k = beg;
        for (; k + 8 <= endn; k += 8) {
            unsigned s0 = sl[k + q];
            unsigned s1 = sl[k + 4 + q];
            uint4 w0 = t[(size_t)s0 * 16 + l16];
            uint4 w1 = t[(size_t)s1 * 16 + l16];
            a0 += bflo(w0.x); a1 += bfhi(w0.x);
            a2 += bflo(w0.y); a3 += bfhi(w0.y);
            a4 += bflo(w0.z); a5 += bfhi(w0.z);
            a6 += bflo(w0.w); a7 += bfhi(w0.w);
            a0 += bflo(w1.x); a1 += bfhi(w1.x);
            a2 += bflo(w1.y); a3 += bfhi(w1.y);
            a4 += bflo(w1.z); a5 += bfhi(w1.z);
            a6 += bflo(w1.w); a7 += bfhi(w1.w);
        }
        if (k + 4 <= endn) {
            unsigned s0 = sl[k + q];
            uint4 w0 = t[(size_t)s0 * 16 + l16];
            a0 += bflo(w0.x); a1 += bfhi(w0.x);
            a2 += bflo(w0.y); a3 += bfhi(w0.y);
            a4 += bflo(w0.z); a5 += bfhi(w0.z);
            a6 += bflo(w0.w); a7 += bfhi(w0.w);
            k += 4;
        }
        int r = endn - k;                 // 0..3
        if (q < r) {
            unsigned s0 = sl[k + q];
            uint4 w0 = t[(size_t)s0 * 16 + l16];
            a0 += bflo(w0.x); a1 += bfhi(w0.x);
            a2 += bflo(w0.y); a3 += bfhi(w0.y);
            a4 += bflo(w0.z); a5 += bfhi(w0.z);
            a6 += bflo(w0.w); a7 += bfhi(w0.w);
        }

        int extra = 0;
        if (m > 0) {                      // rare partition spill
            for (int j = q; j < m; j += 4) {
                int2 e = ovfD[j];
                if (e.x == node) {
                    uint4 w = t[(size_t)e.y * 16 + l16];
                    a0 += bflo(w.x); a1 += bfhi(w.x);
                    a2 += bflo(w.y); a3 += bfhi(w.y);
                    a4 += bflo(w.z); a5 += bfhi(w.z);
                    a6 += bflo(w.w); a7 += bfhi(w.w);
                    ++extra;
                }
            }
        }

        // combine quarters (xor 16, then 32; l16 preserved)
        a0 += __shfl_xor(a0, 16, 64); a1 += __shfl_xor(a1, 16, 64);
        a2 += __shfl_xor(a2, 16, 64); a3 += __shfl_xor(a3, 16, 64);
        a4 += __shfl_xor(a4, 16, 64); a5 += __shfl_xor(a5, 16, 64);
        a6 += __shfl_xor(a6, 16, 64); a7 += __shfl_xor(a7, 16, 64);
        a0 += __shfl_xor(a0, 32, 64); a1 += __shfl_xor(a1, 32, 64);
        a2 += __shfl_xor(a2, 32, 64); a3 += __shfl_xor(a3, 32, 64);
        a4 += __shfl_xor(a4, 32, 64); a5 += __shfl_xor(a5, 32, 64);
        a6 += __shfl_xor(a6, 32, 64); a7 += __shfl_xor(a7, 32, 64);
        if (m > 0) {
            extra += __shfl_xor(extra, 16, 64);
            extra += __shfl_xor(extra, 32, 64);
        }

        if (lane < 16) {
            float inorm = rsqrtf((float)max(deg + extra, 1));
            float* orow = out + (size_t)node * DFEAT + l16 * 8;
            ((float4*)orow)[0] = make_float4(a0 * inorm, a1 * inorm,
                                             a2 * inorm, a3 * inorm);
            ((float4*)orow)[1] = make_float4(a4 * inorm, a5 * inorm,
                                             a6 * inorm, a7 * inorm);
        }
    }
}

// ---------------- fallback: round-5 random-atomic build ----------------
__global__ void build_kernel(const int* __restrict__ src,
                             const int* __restrict__ dst,
                             int* __restrict__ ideg,
                             int* __restrict__ odeg,
                             int* __restrict__ slack,
                             int2* __restrict__ ovf2,
                             int* __restrict__ ovf2_cnt,
                             int nE) {
    int t = blockIdx.x * blockDim.x + threadIdx.x;
    long base = (long)t * 4;
    if (base >= nE) return;
    long lim = base + 4 < (long)nE ? base + 4 : (long)nE;
    for (long e = base; e < lim; ++e) {
        int s = src[e], d = dst[e];
        atomicAdd(&odeg[s], 1);
        int p = atomicAdd(&ideg[d], 1);
        if (p < SLACK) {
            slack[(size_t)d * SLACK + p] = s;
        } else {
            int q = atomicAdd(ovf2_cnt, 1);
            if (q < OVF2_CAP) ovf2[q] = make_int2(d, s);
        }
    }
}

__launch_bounds__(256)
__global__ void aggregate_f32_kernel(const float* __restrict__ u_f,
                                     const float* __restrict__ v_f,
                                     const int* __restrict__ slack,
                                     const int* __restrict__ ideg,
                                     const int* __restrict__ odeg,
                                     const int2* __restrict__ ovf2,
                                     const int* __restrict__ ovf2_cnt,
                                     float* __restrict__ out,
                                     int nN, int nU) {
    int lane = threadIdx.x & 63;
    int wid  = threadIdx.x >> 6;
    int node = blockIdx.x * 4 + wid;
    if (node >= nN) return;

    int deg = ideg[node];
    int cnt = min(deg, SLACK);
    int   sb = 0;
    float nb = 0.f;
    if (lane < cnt) {
        sb = slack[(size_t)node * SLACK + lane];
        nb = rsqrtf((float)max(odeg[sb], 1));
    }
    float2 acc = make_float2(0.f, 0.f);
    for (int k = 0; k < cnt; ++k) {
        int   sk = __shfl(sb, k, 64);
        float nk = __shfl(nb, k, 64);
        const float* row = (sk < nU) ? (u_f + (size_t)sk * DFEAT)
                                     : (v_f + (size_t)(sk - nU) * DFEAT);
        float2 v = ((const float2*)row)[lane];
        acc.x += v.x * nk;
        acc.y += v.y * nk;
    }
    if (deg > SLACK) {
        int m = *ovf2_cnt; if (m > OVF2_CAP) m = OVF2_CAP;
        for (int j = 0; j < m; ++j) {
            int2 os = ovf2[j];
            if (os.x == node) {
                int sk = os.y;
                float nk = rsqrtf((float)max(odeg[sk], 1));
                const float* row = (sk < nU) ? (u_f + (size_t)sk * DFEAT)
                                             : (v_f + (size_t)(sk - nU) * DFEAT);
                float2 v = ((const float2*)row)[lane];
                acc.x += v.x * nk;
                acc.y += v.y * nk;
            }
        }
    }
    float inorm = rsqrtf((float)max(deg, 1));
    acc.x *= inorm; acc.y *= inorm;
    ((float2*)(out + (size_t)node * DFEAT))[lane] = acc;
}

extern "C" void kernel_launch(void* const* d_in, const int* in_sizes, int n_in,
                              void* d_out, int out_size, void* d_ws, size_t ws_size,
                              hipStream_t stream) {
    const float* u_f = (const float*)d_in[0];
    const float* v_f = (const float*)d_in[1];
    const int*   src = (const int*)d_in[2];
    const int*   dst = (const int*)d_in[3];
    float* out = (float*)d_out;

    int nU = in_sizes[0] / DFEAT;
    int nV = in_sizes[1] / DFEAT;
    int nN = nU + nV;
    int nE = in_sizes[2];
    int nbuk = (nN + BNODES - 1) >> BSHIFT;

    // ---- new-path workspace layout (ints) ----
    // odeg | cnts | ovfD | gcurD | gcurS | (partS ∪ tbl region) | partD
    int*  odeg  = (int*)d_ws;
    int*  cnts  = odeg + nN;                 // [1] = ovfD_cnt
    int2* ovfD  = (int2*)(cnts + 8);
    int*  gcurD = (int*)(ovfD + OVFD_CAP);
    int*  gcurS = gcurD + MAXBUK;
    unsigned* partS = (unsigned*)(gcurS + MAXBUK);
    unsigned short* tbl = (unsigned short*)partS;   // overlays partS (dead after P2s)
    size_t partInts = (size_t)nbuk * BCAP;
    size_t tblInts  = (size_t)nN * (DFEAT / 2);
    size_t unionInts = partInts > tblInts ? partInts : tblInts;
    unsigned* partD = partS + unionInts;
    size_t fixedInts = (size_t)nN + 8 + 2 * (size_t)OVFD_CAP + 2 * MAXBUK;
    size_t needNew   = (fixedInts + unionInts + partInts) * 4;
    bool use_new = (nN <= (MAXBUK << BSHIFT)) && (nN < (1 << 24))
                   && (ws_size >= needNew);

    if (use_new) {
        hipMemsetAsync(d_ws, 0, ((size_t)nN + 8) * sizeof(int), stream);
        int nCh = (nE + CH - 1) / CH;
        init_kernel<<<(nbuk + 255) / 256, 256, 0, stream>>>(gcurD, gcurS, nbuk);
        partition_keys_kernel<<<nCh, 256, 0, stream>>>(src, gcurS, partS, odeg,
                                                       nE, nbuk);
        odeg_phase2_kernel<<<nbuk, 256, 0, stream>>>(partS, gcurS, odeg, nN);
        partition_pairs_kernel<<<nCh, 256, 0, stream>>>(dst, src, gcurD, partD,
                                                        ovfD, cnts + 1, nE, nbuk);
        {   // cast AFTER odeg_phase2: tbl overwrites partS (dead)
            long n4 = (long)nN * 32;
            cast_kernel<<<(int)((n4 + 255) / 256), 256, 0, stream>>>(
                u_f, v_f, odeg, tbl, nN, nU);
        }
        agg_fused_kernel<<<nbuk, 512, 0, stream>>>(tbl, partD, gcurD,
                                                   ovfD, cnts + 1, out, nN);
    } else {
        // ---- fallback: round-5 layout ----
        int*  f_ideg = (int*)d_ws;
        int*  f_odeg = f_ideg + nN;
        int*  f_cnts = f_odeg + nN;          // [0] = ovf2_cnt
        int2* f_ovf2 = (int2*)(f_cnts + 8);
        int*  f_slack = (int*)(f_ovf2 + OVF2_CAP);

        hipMemsetAsync(d_ws, 0, ((size_t)2 * nN + 8) * sizeof(int), stream);
        long nT = ((long)nE + 3) / 4;
        build_kernel<<<(int)((nT + 255) / 256), 256, 0, stream>>>(
            src, dst, f_ideg, f_odeg, f_slack, f_ovf2, f_cnts + 0, nE);
        aggregate_f32_kernel<<<(nN + 3) / 4, 256, 0, stream>>>(
            u_f, v_f, f_slack, f_ideg, f_odeg, f_ovf2, f_cnts + 0, out, nN, nU);
    }
}

// Round 13
// 166.419 us; speedup vs baseline: 2.1720x; 1.2544x over previous
//
#include <hip/hip_runtime.h>

// GCN aggregation — single-pass dual partition + fused odeg/cast +
// fused (LDS-sort + full-row gather) aggregate, bf16 prescaled table.
//   out = diag(in_deg^-1/2) * A * diag(out_deg^-1/2) * concat(u_f, v_f)
//
// Pipeline (5 dispatches + 1 memset):
//   init  : gcurD[b]=gcurS[b]=b*BCAP
//   Pboth : ONE pass over (src,dst): dst-bucketed packed pairs -> partD,
//           src-key partition -> partS. Dual LDS histograms; the two
//           1024-bin scans run on waves 0-3 (D) and 4-7 (S); pairs staged
//           + flushed, stage buffer reused for keys.
//   ocast : block per src-bucket: LDS histogram of partS window (= odeg),
//           + spill counts, then cast the bucket's 128 rows:
//           tbl[node][128] = bf16(node_f * rsqrt(max(odeg,1)))
//   agg   : block per dst-bucket (512 thr): LDS counting-sort of packed
//           pairs, then wave-per-node full-row gather (quarter-wave pairing,
//           uint4/lane, k+=8 unroll), shfl_xor reduce, fused in-norm.
//
// Fallback (small ws): round-5 slack-CSR random-atomic build + f32 gather.

#define DFEAT 128
#define SLACK 64            // fallback only
#define OVF2_CAP 65536      // fallback only
#define OVFD_CAP 16384
#define BSHIFT 7
#define BNODES 128
#define MAXBUK 1024         // supports nN <= 131072
#define BCAP 2560           // mean 2048, sd~45 -> 11 sigma slack
#define CH 5888             // edges per partition chunk

// ---------------- init ----------------
__global__ void init_kernel(int* __restrict__ gcurD, int* __restrict__ gcurS,
                            int nbuk) {
    int b = blockIdx.x * blockDim.x + threadIdx.x;
    if (b < nbuk) { gcurD[b] = b * BCAP; gcurS[b] = b * BCAP; }
}

// ---------------- single-pass dual partition ----------------
__global__ __launch_bounds__(512)
void partition_both_kernel(const int* __restrict__ src,
                           const int* __restrict__ dst,
                           int* __restrict__ gcurD,
                           int* __restrict__ gcurS,
                           unsigned* __restrict__ partD,   // packed dl<<24|src
                           unsigned* __restrict__ partS,   // src node id
                           int2* __restrict__ ovfD,
                           int* __restrict__ ovfD_cnt,
                           int* __restrict__ odeg_sp,      // key spills
                           int nE, int nbuk) {
    __shared__ int histD[MAXBUK], dltD[MAXBUK];
    __shared__ int histS[MAXBUK], dltS[MAXBUK];
    __shared__ int wsum[8];
    __shared__ unsigned sk[CH], sv[CH];

    int tid = threadIdx.x;
    long base = (long)blockIdx.x * CH;
    int n = (int)(((long)nE - base) < CH ? ((long)nE - base) : CH);
    if (n <= 0) return;

    for (int b = tid; b < nbuk; b += 512) { histD[b] = 0; histS[b] = 0; }
    __syncthreads();

    // both histograms in one read pass
    for (int i = tid; i < n; i += 512) {
        atomicAdd(&histD[((unsigned)dst[base + i]) >> BSHIFT], 1);
        atomicAdd(&histS[((unsigned)src[base + i]) >> BSHIFT], 1);
    }
    __syncthreads();

    // dual exclusive scan: waves 0-3 handle D, waves 4-7 handle S
    {
        int lane = tid & 63, wid = tid >> 6;
        bool isS = (wid >= 4);
        int* hist = isS ? histS : histD;
        int* dlt  = isS ? dltS  : dltD;
        int* gcur = isS ? gcurS : gcurD;
        int b0 = (isS ? (tid - 256) : tid) * 4;

        int c0 = 0, c1 = 0, c2 = 0, c3 = 0, sum = 0;
        if (b0 < nbuk) {
            c0 = hist[b0];
            c1 = (b0 + 1 < nbuk) ? hist[b0 + 1] : 0;
            c2 = (b0 + 2 < nbuk) ? hist[b0 + 2] : 0;
            c3 = (b0 + 3 < nbuk) ? hist[b0 + 3] : 0;
            sum = c0 + c1 + c2 + c3;
        }
        int x = sum;
        #pragma unroll
        for (int off = 1; off < 64; off <<= 1) {
            int t = __shfl_up(x, off, 64);
            if (lane >= off) x += t;
        }
        if (lane == 63) wsum[wid] = x;
        __syncthreads();
        int wpre = 0;
        for (int w = (isS ? 4 : 0); w < wid; ++w) wpre += wsum[w];
        int excl = wpre + x - sum;
        if (b0 < nbuk) {
            int lb = excl;
            hist[b0] = lb;
            if (c0) { int g = atomicAdd(&gcur[b0], c0); dlt[b0] = g - lb; }
            lb += c0;
            if (b0 + 1 < nbuk) {
                hist[b0 + 1] = lb;
                if (c1) { int g = atomicAdd(&gcur[b0 + 1], c1); dlt[b0 + 1] = g - lb; }
                lb += c1;
            }
            if (b0 + 2 < nbuk) {
                hist[b0 + 2] = lb;
                if (c2) { int g = atomicAdd(&gcur[b0 + 2], c2); dlt[b0 + 2] = g - lb; }
                lb += c2;
            }
            if (b0 + 3 < nbuk) {
                hist[b0 + 3] = lb;
                if (c3) { int g = atomicAdd(&gcur[b0 + 3], c3); dlt[b0 + 3] = g - lb; }
            }
        }
    }
    __syncthreads();

    // pairs: scatter into LDS stage (bucket-sorted), then coalesced flush
    for (int i = tid; i < n; i += 512) {
        unsigned d = (unsigned)dst[base + i];
        unsigned s = (unsigned)src[base + i];
        int slot = atomicAdd(&histD[d >> BSHIFT], 1);
        sk[slot] = d; sv[slot] = s;
    }
    __syncthreads();
    for (int i = tid; i < n; i += 512) {
        unsigned d = sk[i], s = sv[i];
        int b = (int)(d >> BSHIFT);
        long dest = (long)dltD[b] + i;
        if (dest < (long)(b + 1) * BCAP) {
            partD[dest] = ((d & (BNODES - 1)) << 24) | s;
        } else {
            int q = atomicAdd(ovfD_cnt, 1);
            if (q < OVFD_CAP) ovfD[q] = make_int2((int)d, (int)s);
        }
    }
    __syncthreads();

    // keys: reuse sk stage
    for (int i = tid; i < n; i += 512) {
        unsigned s = (unsigned)src[base + i];
        int slot = atomicAdd(&histS[s >> BSHIFT], 1);
        sk[slot] = s;
    }
    __syncthreads();
    for (int i = tid; i < n; i += 512) {
        unsigned k = sk[i];
        int b = (int)(k >> BSHIFT);
        long dest = (long)dltS[b] + i;
        if (dest < (long)(b + 1) * BCAP) partS[dest] = k;
        else atomicAdd(&odeg_sp[k], 1);
    }
}

// ---------------- bf16 helpers ----------------
__device__ __forceinline__ unsigned short f2bf(float x) {
    unsigned u = __float_as_uint(x);
    u += 0x7fffu + ((u >> 16) & 1u);   // round-to-nearest-even
    return (unsigned short)(u >> 16);
}
__device__ __forceinline__ float bflo(unsigned u) { return __uint_as_float(u << 16); }
__device__ __forceinline__ float bfhi(unsigned u) { return __uint_as_float(u & 0xffff0000u); }

// ---------------- fused odeg histogram + cast ----------------
// Block per src-bucket: bins = out-degree of the bucket's 128 nodes, then
// cast those rows: tbl[node][128] = bf16(node_f * rsqrt(max(odeg,1))).
__global__ __launch_bounds__(256)
void odeg_cast_kernel(const unsigned* __restrict__ partS,
                      const int* __restrict__ gcurS,
                      const int* __restrict__ odeg_sp,
                      const float* __restrict__ u_f,
                      const float* __restrict__ v_f,
                      unsigned short* __restrict__ tbl,
                      int nN, int nU) {
    __shared__ int bins[BNODES];
    __shared__ float norms[BNODES];
    int tid = threadIdx.x;
    int bucket = blockIdx.x;
    int nodeBase = bucket << BSHIFT;

    if (tid < BNODES) bins[tid] = 0;
    __syncthreads();

    int start = bucket * BCAP;
    int endv  = gcurS[bucket];
    if (endv > start + BCAP) endv = start + BCAP;
    for (int i = start + tid; i < endv; i += 256)
        atomicAdd(&bins[(int)partS[i] - nodeBase], 1);
    __syncthreads();

    if (tid < BNODES) {
        int node = nodeBase + tid;
        int d = (node < nN) ? (bins[tid] + odeg_sp[node]) : 1;
        norms[tid] = rsqrtf((float)max(d, 1));
    }
    __syncthreads();

    // cast 128 rows x 32 float4
    for (int idx = tid; idx < BNODES * 32; idx += 256) {
        int nl = idx >> 5, q = idx & 31;
        int node = nodeBase + nl;
        if (node >= nN) continue;
        float norm = norms[nl];
        const float* basep = (node < nU) ? (u_f + (size_t)node * DFEAT)
                                         : (v_f + (size_t)(node - nU) * DFEAT);
        float4 v = ((const float4*)basep)[q];
        ushort4 o;
        o.x = f2bf(v.x * norm);
        o.y = f2bf(v.y * norm);
        o.z = f2bf(v.z * norm);
        o.w = f2bf(v.w * norm);
        ((ushort4*)tbl)[(size_t)node * 32 + q] = o;
    }
}

// ---------------- aggregate: fused LDS sort + full-row gather ----------------
__global__ __launch_bounds__(512)
void agg_fused_kernel(const unsigned short* __restrict__ tbl,
                      const unsigned* __restrict__ part,
                      const int* __restrict__ gcur,
                      const int2* __restrict__ ovfD,
                      const int* __restrict__ ovfD_cnt,
                      float* __restrict__ out,
                      int nN) {
    __shared__ unsigned sl[BCAP];
    __shared__ int bins[BNODES];    // counts -> noffs
    __shared__ int curs[BNODES];    // running cursor -> end offsets
    __shared__ int w0tot_s;

    int tid = threadIdx.x;
    int bucket = blockIdx.x;
    int nodeBase = bucket << BSHIFT;
    int lane = tid & 63;
    int wv   = tid >> 6;           // 0..7

    if (tid < BNODES) bins[tid] = 0;
    __syncthreads();

    int start = bucket * BCAP;
    int endv  = gcur[bucket];
    if (endv > start + BCAP) endv = start + BCAP;
    int n = endv - start;

    for (int i = tid; i < n; i += 512)
        atomicAdd(&bins[part[start + i] >> 24], 1);
    __syncthreads();

    int v = 0, x = 0;
    if (tid < BNODES) {
        v = bins[tid];
        x = v;
        #pragma unroll
        for (int off = 1; off < 64; off <<= 1) {
            int t = __shfl_up(x, off, 64);
            if (lane >= off) x += t;
        }
        if (tid == 63) w0tot_s = x;
    }
    __syncthreads();
    if (tid < BNODES) {
        int excl = x - v + ((tid >= 64) ? w0tot_s : 0);
        bins[tid] = excl;
        curs[tid] = excl;
    }
    __syncthreads();

    for (int i = tid; i < n; i += 512) {
        unsigned p = part[start + i];
        int dl = (int)(p >> 24);
        int pos = atomicAdd(&curs[dl], 1);
        sl[pos] = p & 0xFFFFFFu;
    }
    __syncthreads();

    int q = lane >> 4;
    int l16 = lane & 15;
    const uint4* t = (const uint4*)tbl;   // 16 uint4 per 256B row
    int m = *ovfD_cnt;                    // 0 in practice
    if (m > OVFD_CAP) m = OVFD_CAP;

    for (int nl = wv; nl < BNODES; nl += 8) {
        int node = nodeBase + nl;
        if (node >= nN) continue;
        int beg  = bins[nl];
        int endn = curs[nl];
        int deg  = endn - beg;

        float a0 = 0.f, a1 = 0.f, a2 = 0.f, a3 = 0.f;
        float a4 = 0.f, a5 = 0.f, a6 = 0.f, a7 = 0.f;

        int k = beg;
        for (; k + 8 <= endn; k += 8) {
            unsigned s0 = sl[k + q];
            unsigned s1 = sl[k + 4 + q];
            uint4 w0 = t[(size_t)s0 * 16 + l16];
            uint4 w1 = t[(size_t)s1 * 16 + l16];
            a0 += bflo(w0.x); a1 += bfhi(w0.x);
            a2 += bflo(w0.y); a3 += bfhi(w0.y);
            a4 += bflo(w0.z); a5 += bfhi(w0.z);
            a6 += bflo(w0.w); a7 += bfhi(w0.w);
            a0 += bflo(w1.x); a1 += bfhi(w1.x);
            a2 += bflo(w1.y); a3 += bfhi(w1.y);
            a4 += bflo(w1.z); a5 += bfhi(w1.z);
            a6 += bflo(w1.w); a7 += bfhi(w1.w);
        }
        if (k + 4 <= endn) {
            unsigned s0 = sl[k + q];
            uint4 w0 = t[(size_t)s0 * 16 + l16];
            a0 += bflo(w0.x); a1 += bfhi(w0.x);
            a2 += bflo(w0.y); a3 += bfhi(w0.y);
            a4 += bflo(w0.z); a5 += bfhi(w0.z);
            a6 += bflo(w0.w); a7 += bfhi(w0.w);
            k += 4;
        }
        int r = endn - k;                 // 0..3
        if (q < r) {
            unsigned s0 = sl[k + q];
            uint4 w0 = t[(size_t)s0 * 16 + l16];
            a0 += bflo(w0.x); a1 += bfhi(w0.x);
            a2 += bflo(w0.y); a3 += bfhi(w0.y);
            a4 += bflo(w0.z); a5 += bfhi(w0.z);
            a6 += bflo(w0.w); a7 += bfhi(w0.w);
        }

        int extra = 0;
        if (m > 0) {                      // rare partition spill
            for (int j = q; j < m; j += 4) {
                int2 e = ovfD[j];
                if (e.x == node) {
                    uint4 w = t[(size_t)e.y * 16 + l16];
                    a0 += bflo(w.x); a1 += bfhi(w.x);
                    a2 += bflo(w.y); a3 += bfhi(w.y);
                    a4 += bflo(w.z); a5 += bfhi(w.z);
                    a6 += bflo(w.w); a7 += bfhi(w.w);
                    ++extra;
                }
            }
        }

        a0 += __shfl_xor(a0, 16, 64); a1 += __shfl_xor(a1, 16, 64);
        a2 += __shfl_xor(a2, 16, 64); a3 += __shfl_xor(a3, 16, 64);
        a4 += __shfl_xor(a4, 16, 64); a5 += __shfl_xor(a5, 16, 64);
        a6 += __shfl_xor(a6, 16, 64); a7 += __shfl_xor(a7, 16, 64);
        a0 += __shfl_xor(a0, 32, 64); a1 += __shfl_xor(a1, 32, 64);
        a2 += __shfl_xor(a2, 32, 64); a3 += __shfl_xor(a3, 32, 64);
        a4 += __shfl_xor(a4, 32, 64); a5 += __shfl_xor(a5, 32, 64);
        a6 += __shfl_xor(a6, 32, 64); a7 += __shfl_xor(a7, 32, 64);
        if (m > 0) {
            extra += __shfl_xor(extra, 16, 64);
            extra += __shfl_xor(extra, 32, 64);
        }

        if (lane < 16) {
            float inorm = rsqrtf((float)max(deg + extra, 1));
            float* orow = out + (size_t)node * DFEAT + l16 * 8;
            ((float4*)orow)[0] = make_float4(a0 * inorm, a1 * inorm,
                                             a2 * inorm, a3 * inorm);
            ((float4*)orow)[1] = make_float4(a4 * inorm, a5 * inorm,
                                             a6 * inorm, a7 * inorm);
        }
    }
}

// ---------------- fallback: round-5 random-atomic build ----------------
__global__ void build_kernel(const int* __restrict__ src,
                             const int* __restrict__ dst,
                             int* __restrict__ ideg,
                             int* __restrict__ odeg,
                             int* __restrict__ slack,
                             int2* __restrict__ ovf2,
                             int* __restrict__ ovf2_cnt,
                             int nE) {
    int t = blockIdx.x * blockDim.x + threadIdx.x;
    long base = (long)t * 4;
    if (base >= nE) return;
    long lim = base + 4 < (long)nE ? base + 4 : (long)nE;
    for (long e = base; e < lim; ++e) {
        int s = src[e], d = dst[e];
        atomicAdd(&odeg[s], 1);
        int p = atomicAdd(&ideg[d], 1);
        if (p < SLACK) {
            slack[(size_t)d * SLACK + p] = s;
        } else {
            int q = atomicAdd(ovf2_cnt, 1);
            if (q < OVF2_CAP) ovf2[q] = make_int2(d, s);
        }
    }
}

__launch_bounds__(256)
__global__ void aggregate_f32_kernel(const float* __restrict__ u_f,
                                     const float* __restrict__ v_f,
                                     const int* __restrict__ slack,
                                     const int* __restrict__ ideg,
                                     const int* __restrict__ odeg,
                                     const int2* __restrict__ ovf2,
                                     const int* __restrict__ ovf2_cnt,
                                     float* __restrict__ out,
                                     int nN, int nU) {
    int lane = threadIdx.x & 63;
    int wid  = threadIdx.x >> 6;
    int node = blockIdx.x * 4 + wid;
    if (node >= nN) return;

    int deg = ideg[node];
    int cnt = min(deg, SLACK);
    int   sb = 0;
    float nb = 0.f;
    if (lane < cnt) {
        sb = slack[(size_t)node * SLACK + lane];
        nb = rsqrtf((float)max(odeg[sb], 1));
    }
    float2 acc = make_float2(0.f, 0.f);
    for (int k = 0; k < cnt; ++k) {
        int   sk = __shfl(sb, k, 64);
        float nk = __shfl(nb, k, 64);
        const float* row = (sk < nU) ? (u_f + (size_t)sk * DFEAT)
                                     : (v_f + (size_t)(sk - nU) * DFEAT);
        float2 v = ((const float2*)row)[lane];
        acc.x += v.x * nk;
        acc.y += v.y * nk;
    }
    if (deg > SLACK) {
        int m = *ovf2_cnt; if (m > OVF2_CAP) m = OVF2_CAP;
        for (int j = 0; j < m; ++j) {
            int2 os = ovf2[j];
            if (os.x == node) {
                int sk = os.y;
                float nk = rsqrtf((float)max(odeg[sk], 1));
                const float* row = (sk < nU) ? (u_f + (size_t)sk * DFEAT)
                                             : (v_f + (size_t)(sk - nU) * DFEAT);
                float2 v = ((const float2*)row)[lane];
                acc.x += v.x * nk;
                acc.y += v.y * nk;
            }
        }
    }
    float inorm = rsqrtf((float)max(deg, 1));
    acc.x *= inorm; acc.y *= inorm;
    ((float2*)(out + (size_t)node * DFEAT))[lane] = acc;
}

extern "C" void kernel_launch(void* const* d_in, const int* in_sizes, int n_in,
                              void* d_out, int out_size, void* d_ws, size_t ws_size,
                              hipStream_t stream) {
    const float* u_f = (const float*)d_in[0];
    const float* v_f = (const float*)d_in[1];
    const int*   src = (const int*)d_in[2];
    const int*   dst = (const int*)d_in[3];
    float* out = (float*)d_out;

    int nU = in_sizes[0] / DFEAT;
    int nV = in_sizes[1] / DFEAT;
    int nN = nU + nV;
    int nE = in_sizes[2];
    int nbuk = (nN + BNODES - 1) >> BSHIFT;

    // ---- new-path workspace layout (ints) ----
    // odeg_sp | cnts | ovfD | gcurD | gcurS | partD | partS | tbl
    int*  odeg_sp = (int*)d_ws;              // nN
    int*  cnts    = odeg_sp + nN;            // 8; [1] = ovfD_cnt
    int2* ovfD    = (int2*)(cnts + 8);
    int*  gcurD   = (int*)(ovfD + OVFD_CAP);
    int*  gcurS   = gcurD + MAXBUK;
    unsigned* partD = (unsigned*)(gcurS + MAXBUK);
    unsigned* partS = partD + (size_t)nbuk * BCAP;
    unsigned short* tbl = (unsigned short*)(partS + (size_t)nbuk * BCAP);
    size_t needNew = ((size_t)nN + 8 + 2 * (size_t)OVFD_CAP + 2 * MAXBUK
                      + 2 * (size_t)nbuk * BCAP + (size_t)nN * (DFEAT / 2)) * 4;
    bool use_new = (nN <= (MAXBUK << BSHIFT)) && (nN < (1 << 24))
                   && (ws_size >= needNew);

    if (use_new) {
        hipMemsetAsync(d_ws, 0, ((size_t)nN + 8) * sizeof(int), stream);
        int nCh = (nE + CH - 1) / CH;
        init_kernel<<<(nbuk + 255) / 256, 256, 0, stream>>>(gcurD, gcurS, nbuk);
        partition_both_kernel<<<nCh, 512, 0, stream>>>(src, dst, gcurD, gcurS,
                                                       partD, partS, ovfD,
                                                       cnts + 1, odeg_sp,
                                                       nE, nbuk);
        odeg_cast_kernel<<<nbuk, 256, 0, stream>>>(partS, gcurS, odeg_sp,
                                                   u_f, v_f, tbl, nN, nU);
        agg_fused_kernel<<<nbuk, 512, 0, stream>>>(tbl, partD, gcurD,
                                                   ovfD, cnts + 1, out, nN);
    } else {
        // ---- fallback: round-5 layout ----
        int*  f_ideg = (int*)d_ws;
        int*  f_odeg = f_ideg + nN;
        int*  f_cnts = f_odeg + nN;          // [0] = ovf2_cnt
        int2* f_ovf2 = (int2*)(f_cnts + 8);
        int*  f_slack = (int*)(f_ovf2 + OVF2_CAP);

        hipMemsetAsync(d_ws, 0, ((size_t)2 * nN + 8) * sizeof(int), stream);
        long nT = ((long)nE + 3) / 4;
        build_kernel<<<(int)((nT + 255) / 256), 256, 0, stream>>>(
            src, dst, f_ideg, f_odeg, f_slack, f_ovf2, f_cnts + 0, nE);
        aggregate_f32_kernel<<<(nN + 3) / 4, 256, 0, stream>>>(
            u_f, v_f, f_slack, f_ideg, f_odeg, f_ovf2, f_cnts + 0, out, nN, nU);
    }
}

// Round 14
// 164.774 us; speedup vs baseline: 2.1936x; 1.0100x over previous
//
#include <hip/hip_runtime.h>

// GCN aggregation — single-pass dual partition + fused odeg/cast +
// fused (LDS-sort + paired full-row gather) aggregate, bf16 prescaled table.
//   out = diag(in_deg^-1/2) * A * diag(out_deg^-1/2) * concat(u_f, v_f)
//
// Pipeline (4 dispatches + 1 memset):
//   Pboth : ONE pass over (src,dst): dst-bucketed packed pairs -> partD,
//           src-key partition -> partS. Dual LDS histograms; dual 1024-bin
//           scans on waves 0-3 / 4-7; stage+flush pairs, then keys.
//           Bucket cursors are RELATIVE (memset-zeroed; no init kernel).
//   ocast : block per src-bucket: LDS histogram of partS window (= odeg),
//           then cast: tbl[node][128] = bf16(node_f * rsqrt(max(odeg,1)))
//   agg   : block per dst-bucket (512 thr): LDS counting-sort, then
//           wave-per-node-PAIR full-row gather (quarter-wave pairing,
//           uint4/lane, 4 gathers in flight), shfl_xor reduce, fused in-norm.
//
// Fallback (small ws): round-5 slack-CSR random-atomic build + f32 gather.

#define DFEAT 128
#define SLACK 64            // fallback only
#define OVF2_CAP 65536      // fallback only
#define OVFD_CAP 16384
#define BSHIFT 7
#define BNODES 128
#define MAXBUK 1024         // supports nN <= 131072
#define BCAP 2560           // mean 2048, sd~45 -> 11 sigma slack
#define CH 8192             // edges per partition chunk (64KB stage)

// ---------------- single-pass dual partition ----------------
// gcurD/gcurS hold RELATIVE per-bucket counts (start at 0 via memset).
__global__ __launch_bounds__(512)
void partition_both_kernel(const int* __restrict__ src,
                           const int* __restrict__ dst,
                           int* __restrict__ gcurD,
                           int* __restrict__ gcurS,
                           unsigned* __restrict__ partD,   // packed dl<<24|src
                           unsigned* __restrict__ partS,   // src node id
                           int2* __restrict__ ovfD,
                           int* __restrict__ ovfD_cnt,
                           int* __restrict__ odeg_sp,      // key spills
                           int nE, int nbuk) {
    __shared__ int histD[MAXBUK], dltD[MAXBUK];
    __shared__ int histS[MAXBUK], dltS[MAXBUK];
    __shared__ int wsum[8];
    __shared__ unsigned sk[CH], sv[CH];

    int tid = threadIdx.x;
    long base = (long)blockIdx.x * CH;
    int n = (int)(((long)nE - base) < CH ? ((long)nE - base) : CH);
    if (n <= 0) return;

    for (int b = tid; b < nbuk; b += 512) { histD[b] = 0; histS[b] = 0; }
    __syncthreads();

    for (int i = tid; i < n; i += 512) {
        atomicAdd(&histD[((unsigned)dst[base + i]) >> BSHIFT], 1);
        atomicAdd(&histS[((unsigned)src[base + i]) >> BSHIFT], 1);
    }
    __syncthreads();

    // dual exclusive scan: waves 0-3 -> D, waves 4-7 -> S
    {
        int lane = tid & 63, wid = tid >> 6;
        bool isS = (wid >= 4);
        int* hist = isS ? histS : histD;
        int* dlt  = isS ? dltS  : dltD;
        int* gcur = isS ? gcurS : gcurD;
        int b0 = (isS ? (tid - 256) : tid) * 4;

        int c0 = 0, c1 = 0, c2 = 0, c3 = 0, sum = 0;
        if (b0 < nbuk) {
            c0 = hist[b0];
            c1 = (b0 + 1 < nbuk) ? hist[b0 + 1] : 0;
            c2 = (b0 + 2 < nbuk) ? hist[b0 + 2] : 0;
            c3 = (b0 + 3 < nbuk) ? hist[b0 + 3] : 0;
            sum = c0 + c1 + c2 + c3;
        }
        int x = sum;
        #pragma unroll
        for (int off = 1; off < 64; off <<= 1) {
            int t = __shfl_up(x, off, 64);
            if (lane >= off) x += t;
        }
        if (lane == 63) wsum[wid] = x;
        __syncthreads();
        int wpre = 0;
        for (int w = (isS ? 4 : 0); w < wid; ++w) wpre += wsum[w];
        int excl = wpre + x - sum;
        if (b0 < nbuk) {
            int lb = excl;
            hist[b0] = lb;
            if (c0) { int g = atomicAdd(&gcur[b0], c0); dlt[b0] = b0 * BCAP + g - lb; }
            lb += c0;
            if (b0 + 1 < nbuk) {
                hist[b0 + 1] = lb;
                if (c1) { int g = atomicAdd(&gcur[b0 + 1], c1); dlt[b0 + 1] = (b0 + 1) * BCAP + g - lb; }
                lb += c1;
            }
            if (b0 + 2 < nbuk) {
                hist[b0 + 2] = lb;
                if (c2) { int g = atomicAdd(&gcur[b0 + 2], c2); dlt[b0 + 2] = (b0 + 2) * BCAP + g - lb; }
                lb += c2;
            }
            if (b0 + 3 < nbuk) {
                hist[b0 + 3] = lb;
                if (c3) { int g = atomicAdd(&gcur[b0 + 3], c3); dlt[b0 + 3] = (b0 + 3) * BCAP + g - lb; }
            }
        }
    }
    __syncthreads();

    // pairs: stage bucket-sorted, flush coalesced
    for (int i = tid; i < n; i += 512) {
        unsigned d = (unsigned)dst[base + i];
        unsigned s = (unsigned)src[base + i];
        int slot = atomicAdd(&histD[d >> BSHIFT], 1);
        sk[slot] = d; sv[slot] = s;
    }
    __syncthreads();
    for (int i = tid; i < n; i += 512) {
        unsigned d = sk[i], s = sv[i];
        int b = (int)(d >> BSHIFT);
        long dest = (long)dltD[b] + i;
        if (dest < (long)(b + 1) * BCAP) {
            partD[dest] = ((d & (BNODES - 1)) << 24) | s;
        } else {
            int q = atomicAdd(ovfD_cnt, 1);
            if (q < OVFD_CAP) ovfD[q] = make_int2((int)d, (int)s);
        }
    }
    __syncthreads();

    // keys: reuse sk stage
    for (int i = tid; i < n; i += 512) {
        unsigned s = (unsigned)src[base + i];
        int slot = atomicAdd(&histS[s >> BSHIFT], 1);
        sk[slot] = s;
    }
    __syncthreads();
    for (int i = tid; i < n; i += 512) {
        unsigned k = sk[i];
        int b = (int)(k >> BSHIFT);
        long dest = (long)dltS[b] + i;
        if (dest < (long)(b + 1) * BCAP) partS[dest] = k;
        else atomicAdd(&odeg_sp[k], 1);
    }
}

// ---------------- bf16 helpers ----------------
__device__ __forceinline__ unsigned short f2bf(float x) {
    unsigned u = __float_as_uint(x);
    u += 0x7fffu + ((u >> 16) & 1u);   // round-to-nearest-even
    return (unsigned short)(u >> 16);
}
__device__ __forceinline__ float bflo(unsigned u) { return __uint_as_float(u << 16); }
__device__ __forceinline__ float bfhi(unsigned u) { return __uint_as_float(u & 0xffff0000u); }

// ---------------- fused odeg histogram + cast ----------------
__global__ __launch_bounds__(256)
void odeg_cast_kernel(const unsigned* __restrict__ partS,
                      const int* __restrict__ gcurS,
                      const int* __restrict__ odeg_sp,
                      const float* __restrict__ u_f,
                      const float* __restrict__ v_f,
                      unsigned short* __restrict__ tbl,
                      int nN, int nU) {
    __shared__ int bins[BNODES];
    __shared__ float norms[BNODES];
    int tid = threadIdx.x;
    int bucket = blockIdx.x;
    int nodeBase = bucket << BSHIFT;

    if (tid < BNODES) bins[tid] = 0;
    __syncthreads();

    int start = bucket * BCAP;
    int cnt = gcurS[bucket]; if (cnt > BCAP) cnt = BCAP;
    int endv = start + cnt;
    for (int i = start + tid; i < endv; i += 256)
        atomicAdd(&bins[(int)partS[i] - nodeBase], 1);
    __syncthreads();

    if (tid < BNODES) {
        int node = nodeBase + tid;
        int d = (node < nN) ? (bins[tid] + odeg_sp[node]) : 1;
        norms[tid] = rsqrtf((float)max(d, 1));
    }
    __syncthreads();

    for (int idx = tid; idx < BNODES * 32; idx += 256) {
        int nl = idx >> 5, q = idx & 31;
        int node = nodeBase + nl;
        if (node >= nN) continue;
        float norm = norms[nl];
        const float* basep = (node < nU) ? (u_f + (size_t)node * DFEAT)
                                         : (v_f + (size_t)(node - nU) * DFEAT);
        float4 v = ((const float4*)basep)[q];
        ushort4 o;
        o.x = f2bf(v.x * norm);
        o.y = f2bf(v.y * norm);
        o.z = f2bf(v.z * norm);
        o.w = f2bf(v.w * norm);
        ((ushort4*)tbl)[(size_t)node * 32 + q] = o;
    }
}

// ---------------- aggregate: fused LDS sort + paired full-row gather --------
#define ACCQ(A0,A1,A2,A3,A4,A5,A6,A7,W)                \
    A0 += bflo((W).x); A1 += bfhi((W).x);              \
    A2 += bflo((W).y); A3 += bfhi((W).y);              \
    A4 += bflo((W).z); A5 += bfhi((W).z);              \
    A6 += bflo((W).w); A7 += bfhi((W).w)

__global__ __launch_bounds__(512)
void agg_fused_kernel(const unsigned short* __restrict__ tbl,
                      const unsigned* __restrict__ part,
                      const int* __restrict__ gcur,
                      const int2* __restrict__ ovfD,
                      const int* __restrict__ ovfD_cnt,
                      float* __restrict__ out,
                      int nN) {
    __shared__ unsigned sl[BCAP];
    __shared__ int bins[BNODES];    // counts -> begin offsets
    __shared__ int curs[BNODES];    // running cursor -> end offsets
    __shared__ int w0tot_s;

    int tid = threadIdx.x;
    int bucket = blockIdx.x;
    int nodeBase = bucket << BSHIFT;
    int lane = tid & 63;
    int wv   = tid >> 6;           // 0..7

    if (tid < BNODES) bins[tid] = 0;
    __syncthreads();

    int start = bucket * BCAP;
    int n = gcur[bucket]; if (n > BCAP) n = BCAP;

    for (int i = tid; i < n; i += 512)
        atomicAdd(&bins[part[start + i] >> 24], 1);
    __syncthreads();

    int v = 0, x = 0;
    if (tid < BNODES) {
        v = bins[tid];
        x = v;
        #pragma unroll
        for (int off = 1; off < 64; off <<= 1) {
            int t = __shfl_up(x, off, 64);
            if (lane >= off) x += t;
        }
        if (tid == 63) w0tot_s = x;
    }
    __syncthreads();
    if (tid < BNODES) {
        int excl = x - v + ((tid >= 64) ? w0tot_s : 0);
        bins[tid] = excl;
        curs[tid] = excl;
    }
    __syncthreads();

    for (int i = tid; i < n; i += 512) {
        unsigned p = part[start + i];
        int dl = (int)(p >> 24);
        int pos = atomicAdd(&curs[dl], 1);
        sl[pos] = p & 0xFFFFFFu;
    }
    __syncthreads();

    int q = lane >> 4;
    int l16 = lane & 15;
    const uint4* t = (const uint4*)tbl;   // 16 uint4 per 256B row
    int m = *ovfD_cnt;                    // 0 in practice
    if (m > OVFD_CAP) m = OVFD_CAP;

    // 8 node-pairs per wave: (wv+16j, wv+8+16j)
    for (int j = 0; j < 8; ++j) {
        int nlA = wv + 16 * j;
        int nlB = nlA + 8;
        int nodeA = nodeBase + nlA;
        int nodeB = nodeBase + nlB;
        int begA = bins[nlA], endA = curs[nlA];
        int begB = bins[nlB], endB = curs[nlB];
        int degA = endA - begA, degB = endB - begB;
        if (nodeA >= nN) endA = begA;
        if (nodeB >= nN) endB = begB;

        float A0=0.f,A1=0.f,A2=0.f,A3=0.f,A4=0.f,A5=0.f,A6=0.f,A7=0.f;
        float B0=0.f,B1=0.f,B2=0.f,B3=0.f,B4=0.f,B5=0.f,B6=0.f,B7=0.f;

        int kA = begA, kB = begB;
        // joint loop: 4 gathers in flight (wave-uniform bounds)
        while (kA + 8 <= endA && kB + 8 <= endB) {
            unsigned sA0 = sl[kA + q];
            unsigned sA1 = sl[kA + 4 + q];
            unsigned sB0 = sl[kB + q];
            unsigned sB1 = sl[kB + 4 + q];
            uint4 wA0 = t[(size_t)sA0 * 16 + l16];
            uint4 wA1 = t[(size_t)sA1 * 16 + l16];
            uint4 wB0 = t[(size_t)sB0 * 16 + l16];
            uint4 wB1 = t[(size_t)sB1 * 16 + l16];
            ACCQ(A0,A1,A2,A3,A4,A5,A6,A7, wA0);
            ACCQ(A0,A1,A2,A3,A4,A5,A6,A7, wA1);
            ACCQ(B0,B1,B2,B3,B4,B5,B6,B7, wB0);
            ACCQ(B0,B1,B2,B3,B4,B5,B6,B7, wB1);
            kA += 8; kB += 8;
        }
        // drain A
        for (; kA + 8 <= endA; kA += 8) {
            unsigned s0 = sl[kA + q];
            unsigned s1 = sl[kA + 4 + q];
            uint4 w0 = t[(size_t)s0 * 16 + l16];
            uint4 w1 = t[(size_t)s1 * 16 + l16];
            ACCQ(A0,A1,A2,A3,A4,A5,A6,A7, w0);
            ACCQ(A0,A1,A2,A3,A4,A5,A6,A7, w1);
        }
        if (kA + 4 <= endA) {
            unsigned s0 = sl[kA + q];
            uint4 w0 = t[(size_t)s0 * 16 + l16];
            ACCQ(A0,A1,A2,A3,A4,A5,A6,A7, w0);
            kA += 4;
        }
        if (q < endA - kA) {
            unsigned s0 = sl[kA + q];
            uint4 w0 = t[(size_t)s0 * 16 + l16];
            ACCQ(A0,A1,A2,A3,A4,A5,A6,A7, w0);
        }
        // drain B
        for (; kB + 8 <= endB; kB += 8) {
            unsigned s0 = sl[kB + q];
            unsigned s1 = sl[kB + 4 + q];
            uint4 w0 = t[(size_t)s0 * 16 + l16];
            uint4 w1 = t[(size_t)s1 * 16 + l16];
            ACCQ(B0,B1,B2,B3,B4,B5,B6,B7, w0);
            ACCQ(B0,B1,B2,B3,B4,B5,B6,B7, w1);
        }
        if (kB + 4 <= endB) {
            unsigned s0 = sl[kB + q];
            uint4 w0 = t[(size_t)s0 * 16 + l16];
            ACCQ(B0,B1,B2,B3,B4,B5,B6,B7, w0);
            kB += 4;
        }
        if (q < endB - kB) {
            unsigned s0 = sl[kB + q];
            uint4 w0 = t[(size_t)s0 * 16 + l16];
            ACCQ(B0,B1,B2,B3,B4,B5,B6,B7, w0);
        }

        int extraA = 0, extraB = 0;
        if (m > 0) {                      // rare partition spill
            for (int jj = q; jj < m; jj += 4) {
                int2 e = ovfD[jj];
                if (e.x == nodeA) {
                    uint4 w = t[(size_t)e.y * 16 + l16];
                    ACCQ(A0,A1,A2,A3,A4,A5,A6,A7, w);
                    ++extraA;
                }
                if (e.x == nodeB) {
                    uint4 w = t[(size_t)e.y * 16 + l16];
                    ACCQ(B0,B1,B2,B3,B4,B5,B6,B7, w);
                    ++extraB;
                }
            }
            extraA += __shfl_xor(extraA, 16, 64);
            extraA += __shfl_xor(extraA, 32, 64);
            extraB += __shfl_xor(extraB, 16, 64);
            extraB += __shfl_xor(extraB, 32, 64);
        }

        A0 += __shfl_xor(A0, 16, 64); A1 += __shfl_xor(A1, 16, 64);
        A2 += __shfl_xor(A2, 16, 64); A3 += __shfl_xor(A3, 16, 64);
        A4 += __shfl_xor(A4, 16, 64); A5 += __shfl_xor(A5, 16, 64);
        A6 += __shfl_xor(A6, 16, 64); A7 += __shfl_xor(A7, 16, 64);
        A0 += __shfl_xor(A0, 32, 64); A1 += __shfl_xor(A1, 32, 64);
        A2 += __shfl_xor(A2, 32, 64); A3 += __shfl_xor(A3, 32, 64);
        A4 += __shfl_xor(A4, 32, 64); A5 += __shfl_xor(A5, 32, 64);
        A6 += __shfl_xor(A6, 32, 64); A7 += __shfl_xor(A7, 32, 64);
        B0 += __shfl_xor(B0, 16, 64); B1 += __shfl_xor(B1, 16, 64);
        B2 += __shfl_xor(B2, 16, 64); B3 += __shfl_xor(B3, 16, 64);
        B4 += __shfl_xor(B4, 16, 64); B5 += __shfl_xor(B5, 16, 64);
        B6 += __shfl_xor(B6, 16, 64); B7 += __shfl_xor(B7, 16, 64);
        B0 += __shfl_xor(B0, 32, 64); B1 += __shfl_xor(B1, 32, 64);
        B2 += __shfl_xor(B2, 32, 64); B3 += __shfl_xor(B3, 32, 64);
        B4 += __shfl_xor(B4, 32, 64); B5 += __shfl_xor(B5, 32, 64);
        B6 += __shfl_xor(B6, 32, 64); B7 += __shfl_xor(B7, 32, 64);

        if (lane < 16) {
            if (nodeA < nN) {
                float in = rsqrtf((float)max(degA + extraA, 1));
                float* orow = out + (size_t)nodeA * DFEAT + l16 * 8;
                ((float4*)orow)[0] = make_float4(A0*in, A1*in, A2*in, A3*in);
                ((float4*)orow)[1] = make_float4(A4*in, A5*in, A6*in, A7*in);
            }
            if (nodeB < nN) {
                float in = rsqrtf((float)max(degB + extraB, 1));
                float* orow = out + (size_t)nodeB * DFEAT + l16 * 8;
                ((float4*)orow)[0] = make_float4(B0*in, B1*in, B2*in, B3*in);
                ((float4*)orow)[1] = make_float4(B4*in, B5*in, B6*in, B7*in);
            }
        }
    }
}

// ---------------- fallback: round-5 random-atomic build ----------------
__global__ void build_kernel(const int* __restrict__ src,
                             const int* __restrict__ dst,
                             int* __restrict__ ideg,
                             int* __restrict__ odeg,
                             int* __restrict__ slack,
                             int2* __restrict__ ovf2,
                             int* __restrict__ ovf2_cnt,
                             int nE) {
    int t = blockIdx.x * blockDim.x + threadIdx.x;
    long base = (long)t * 4;
    if (base >= nE) return;
    long lim = base + 4 < (long)nE ? base + 4 : (long)nE;
    for (long e = base; e < lim; ++e) {
        int s = src[e], d = dst[e];
        atomicAdd(&odeg[s], 1);
        int p = atomicAdd(&ideg[d], 1);
        if (p < SLACK) {
            slack[(size_t)d * SLACK + p] = s;
        } else {
            int q = atomicAdd(ovf2_cnt, 1);
            if (q < OVF2_CAP) ovf2[q] = make_int2(d, s);
        }
    }
}

__launch_bounds__(256)
__global__ void aggregate_f32_kernel(const float* __restrict__ u_f,
                                     const float* __restrict__ v_f,
                                     const int* __restrict__ slack,
                                     const int* __restrict__ ideg,
                                     const int* __restrict__ odeg,
                                     const int2* __restrict__ ovf2,
                                     const int* __restrict__ ovf2_cnt,
                                     float* __restrict__ out,
                                     int nN, int nU) {
    int lane = threadIdx.x & 63;
    int wid  = threadIdx.x >> 6;
    int node = blockIdx.x * 4 + wid;
    if (node >= nN) return;

    int deg = ideg[node];
    int cnt = min(deg, SLACK);
    int   sb = 0;
    float nb = 0.f;
    if (lane < cnt) {
        sb = slack[(size_t)node * SLACK + lane];
        nb = rsqrtf((float)max(odeg[sb], 1));
    }
    float2 acc = make_float2(0.f, 0.f);
    for (int k = 0; k < cnt; ++k) {
        int   sk = __shfl(sb, k, 64);
        float nk = __shfl(nb, k, 64);
        const float* row = (sk < nU) ? (u_f + (size_t)sk * DFEAT)
                                     : (v_f + (size_t)(sk - nU) * DFEAT);
        float2 v = ((const float2*)row)[lane];
        acc.x += v.x * nk;
        acc.y += v.y * nk;
    }
    if (deg > SLACK) {
        int m = *ovf2_cnt; if (m > OVF2_CAP) m = OVF2_CAP;
        for (int j = 0; j < m; ++j) {
            int2 os = ovf2[j];
            if (os.x == node) {
                int sk = os.y;
                float nk = rsqrtf((float)max(odeg[sk], 1));
                const float* row = (sk < nU) ? (u_f + (size_t)sk * DFEAT)
                                             : (v_f + (size_t)(sk - nU) * DFEAT);
                float2 v = ((const float2*)row)[lane];
                acc.x += v.x * nk;
                acc.y += v.y * nk;
            }
        }
    }
    float inorm = rsqrtf((float)max(deg, 1));
    acc.x *= inorm; acc.y *= inorm;
    ((float2*)(out + (size_t)node * DFEAT))[lane] = acc;
}

extern "C" void kernel_launch(void* const* d_in, const int* in_sizes, int n_in,
                              void* d_out, int out_size, void* d_ws, size_t ws_size,
                              hipStream_t stream) {
    const float* u_f = (const float*)d_in[0];
    const float* v_f = (const float*)d_in[1];
    const int*   src = (const int*)d_in[2];
    const int*   dst = (const int*)d_in[3];
    float* out = (float*)d_out;

    int nU = in_sizes[0] / DFEAT;
    int nV = in_sizes[1] / DFEAT;
    int nN = nU + nV;
    int nE = in_sizes[2];
    int nbuk = (nN + BNODES - 1) >> BSHIFT;

    // ---- new-path workspace layout (ints) ----
    // odeg_sp | cnts | gcurD | gcurS | ovfD | partD | partS | tbl
    // (odeg_sp..gcurS contiguous -> one memset zeroes them all)
    int*  odeg_sp = (int*)d_ws;              // nN
    int*  cnts    = odeg_sp + nN;            // 8; [1] = ovfD_cnt
    int*  gcurD   = cnts + 8;                // MAXBUK (relative counts)
    int*  gcurS   = gcurD + MAXBUK;          // MAXBUK
    int2* ovfD    = (int2*)(gcurS + MAXBUK);
    unsigned* partD = (unsigned*)(ovfD + OVFD_CAP);
    unsigned* partS = partD + (size_t)nbuk * BCAP;
    unsigned short* tbl = (unsigned short*)(partS + (size_t)nbuk * BCAP);
    size_t needNew = ((size_t)nN + 8 + 2 * MAXBUK + 2 * (size_t)OVFD_CAP
                      + 2 * (size_t)nbuk * BCAP + (size_t)nN * (DFEAT / 2)) * 4;
    bool use_new = (nN <= (MAXBUK << BSHIFT)) && (nN < (1 << 24))
                   && (ws_size >= needNew);

    if (use_new) {
        hipMemsetAsync(d_ws, 0, ((size_t)nN + 8 + 2 * MAXBUK) * sizeof(int), stream);
        int nCh = (nE + CH - 1) / CH;
        partition_both_kernel<<<nCh, 512, 0, stream>>>(src, dst, gcurD, gcurS,
                                                       partD, partS, ovfD,
                                                       cnts + 1, odeg_sp,
                                                       nE, nbuk);
        odeg_cast_kernel<<<nbuk, 256, 0, stream>>>(partS, gcurS, odeg_sp,
                                                   u_f, v_f, tbl, nN, nU);
        agg_fused_kernel<<<nbuk, 512, 0, stream>>>(tbl, partD, gcurD,
                                                   ovfD, cnts + 1, out, nN);
    } else {
        // ---- fallback: round-5 layout ----
        int*  f_ideg = (int*)d_ws;
        int*  f_odeg = f_ideg + nN;
        int*  f_cnts = f_odeg + nN;          // [0] = ovf2_cnt
        int2* f_ovf2 = (int2*)(f_cnts + 8);
        int*  f_slack = (int*)(f_ovf2 + OVF2_CAP);

        hipMemsetAsync(d_ws, 0, ((size_t)2 * nN + 8) * sizeof(int), stream);
        long nT = ((long)nE + 3) / 4;
        build_kernel<<<(int)((nT + 255) / 256), 256, 0, stream>>>(
            src, dst, f_ideg, f_odeg, f_slack, f_ovf2, f_cnts + 0, nE);
        aggregate_f32_kernel<<<(nN + 3) / 4, 256, 0, stream>>>(
            u_f, v_f, f_slack, f_ideg, f_odeg, f_ovf2, f_cnts + 0, out, nN, nU);
    }
}